// Round 4
// baseline (10557.388 us; speedup 1.0000x reference)
//
#include <hip/hip_runtime.h>
#include <math.h>

// Backprop_29188597744223 — 1024-step sequential MLP training scan.
//
//   k_gram : G = X·Xᵀ (lower triangle + diag tiles), grid-parallel
//   k_z10  : Z10 = X·W1_init, grid-parallel
//   k2_seq : ONE workgroup, 512 threads (8 waves). 6 barrier-fenced phases:
//              A : replicated scalar recurrences (f64 n1 + n2/n3 chains, all
//                  threads, inputs from dpart) + deferred W2/W3 rank-1 update
//                  + z1 history (4-way split) + a1 + |a1|² dot
//              B1: z2 partials -> scr
//              B2: z2 reduce, a2, |a2|² dot
//              C1: z3 partials -> scr (transposed [p][2q] float2 layout)
//              CE: per-half-wave redundant softmax/d3/b3 + o2 via in-group
//                  DPP split-tree + b2 + dots (C2+E1+E2 merged, no barriers)
//              F : o1 partials + in-group DPP split-tree + zo/b1 + dots
//                  (F1+F2 merged)
//            In-group tree: 16 values over 32 lanes; xor1/2 = quad_perm DPP,
//            xor4/8 = row_shl/shr + select, xor16 = one shfl. End mapping:
//            lane gl holds row p*16 + (gl&15).
//            Lazy scales s2/s3 (registers, replicated); biases pre-norm with
//            rb folded at use; per-block tail runs the chain for step 63
//            before the o1/c flush. No global stores in the step loop.
//   k_w1out: W1_final = s1_f·(W1_init + Xᵀ·diag(c)·O1), grid-parallel

#define LRC  0.01f
#define EPSV 1e-8f

typedef float f32x8 __attribute__((ext_vector_type(8)));

#define SMEM_FLOATS 36456
#define SMEM_BYTES  (SMEM_FLOATS * 4)

#define ROWS16(OP)                                                            \
  OP(0) OP(1) OP(2) OP(3) OP(4) OP(5) OP(6) OP(7)                             \
  OP(8) OP(9) OP(10) OP(11) OP(12) OP(13) OP(14) OP(15)

__device__ __forceinline__ float hsum8(f32x8 v) {
  return ((v.s0 + v.s1) + (v.s2 + v.s3)) + ((v.s4 + v.s5) + (v.s6 + v.s7));
}

// ---- DPP helpers (VALU-rate; no DS pipe) -----------------------------------
template <int CTRL>
__device__ __forceinline__ float dpp_mov(float x) {
  return __builtin_bit_cast(float, __builtin_amdgcn_update_dpp(
      0, __builtin_bit_cast(int, x), CTRL, 0xf, 0xf, true));
}
template <int CTRL>
__device__ __forceinline__ float dpp_add(float v) {
  return v + dpp_mov<CTRL>(v);
}
// Full 64-lane sum, broadcast via readlane(63).
__device__ __forceinline__ float dpp_allred64(float v) {
  v = dpp_add<0x111>(v);   // row_shr:1
  v = dpp_add<0x112>(v);   // row_shr:2
  v = dpp_add<0x114>(v);   // row_shr:4
  v = dpp_add<0x118>(v);   // row_shr:8
  v = dpp_add<0x142>(v);   // row_bcast:15
  v = dpp_add<0x143>(v);   // row_bcast:31 -> lane 63 holds total
  return __builtin_bit_cast(float,
      __builtin_amdgcn_readlane(__builtin_bit_cast(int, v), 63));
}
// xor-exchange at distance 4/8 within a 16-lane row (both directions + select)
__device__ __forceinline__ float dpp_xor4(float x, bool hi) {
  const float up = dpp_mov<0x104>(x);   // row_shl:4 : Dst[i]=Src[i+4]
  const float dn = dpp_mov<0x114>(x);   // row_shr:4 : Dst[i]=Src[i-4]
  return hi ? dn : up;
}
__device__ __forceinline__ float dpp_xor8(float x, bool hi) {
  const float up = dpp_mov<0x108>(x);   // row_shl:8
  const float dn = dpp_mov<0x118>(x);   // row_shr:8
  return hi ? dn : up;
}

__device__ __forceinline__ float wave_allred(float v) {  // init-path only
#pragma unroll
  for (int off = 32; off > 0; off >>= 1) v += __shfl_xor(v, off);
  return v;
}

// In-group (32-lane) split-tree over 16 values v[0..15]; after this, every
// lane holds the full 32-lane sum for index (lane&15) in v[0].
#define TSTAGE(XEXPR, BITVAL, N2)                                             \
  { _Pragma("unroll")                                                         \
    for (int s = 0; s < N2; s++) {                                            \
      const float aa = v[2 * s], bb = v[2 * s + 1];                           \
      const float snd = (BITVAL) ? aa : bb;                                   \
      const float kp = (BITVAL) ? bb : aa;                                    \
      v[s] = kp + (XEXPR);                                                    \
    } }
#define TREE16()                                                              \
  TSTAGE(dpp_mov<0xB1>(snd), bt1, 8)                                          \
  TSTAGE(dpp_mov<0x4E>(snd), bt2, 4)                                          \
  TSTAGE(dpp_xor4(snd, bt4), bt4, 2)                                          \
  TSTAGE(dpp_xor8(snd, bt8), bt8, 1)                                          \
  v[0] += __shfl_xor(v[0], 16);

#define FMA16(c, a, b)                                                        \
  c[0][0] += a.x * b.x; c[0][1] += a.x * b.y; c[0][2] += a.x * b.z; c[0][3] += a.x * b.w; \
  c[1][0] += a.y * b.x; c[1][1] += a.y * b.y; c[1][2] += a.y * b.z; c[1][3] += a.y * b.w; \
  c[2][0] += a.z * b.x; c[2][1] += a.z * b.y; c[2][2] += a.z * b.z; c[2][3] += a.z * b.w; \
  c[3][0] += a.w * b.x; c[3][1] += a.w * b.y; c[3][2] += a.w * b.z; c[3][3] += a.w * b.w;

// ---------------------------------------------------------------- k_gram ----
__global__ __launch_bounds__(256) void k_gram(const float* __restrict__ X,
                                              float* __restrict__ G) {
  const int bi = blockIdx.y, bj = blockIdx.x;
  if (bj > bi) return;
  __shared__ float Xa[32][68];
  __shared__ float Xb[32][68];
  const int tid = threadIdx.x;
  const int tx = tid & 15, ty = tid >> 4;
  float c[4][4] = {};
  for (int k0 = 0; k0 < 1024; k0 += 32) {
    __syncthreads();
    {
      const int row = tid >> 2, kk = (tid & 3) * 8;
      const float* pa = X + (bi * 64 + row) * 1024 + k0 + kk;
      const float4 a0 = *(const float4*)pa;
      const float4 a1 = *(const float4*)(pa + 4);
      Xa[kk + 0][row] = a0.x; Xa[kk + 1][row] = a0.y;
      Xa[kk + 2][row] = a0.z; Xa[kk + 3][row] = a0.w;
      Xa[kk + 4][row] = a1.x; Xa[kk + 5][row] = a1.y;
      Xa[kk + 6][row] = a1.z; Xa[kk + 7][row] = a1.w;
      const float* pb = X + (bj * 64 + row) * 1024 + k0 + kk;
      const float4 b0 = *(const float4*)pb;
      const float4 b1 = *(const float4*)(pb + 4);
      Xb[kk + 0][row] = b0.x; Xb[kk + 1][row] = b0.y;
      Xb[kk + 2][row] = b0.z; Xb[kk + 3][row] = b0.w;
      Xb[kk + 4][row] = b1.x; Xb[kk + 5][row] = b1.y;
      Xb[kk + 6][row] = b1.z; Xb[kk + 7][row] = b1.w;
    }
    __syncthreads();
#pragma unroll
    for (int kk = 0; kk < 32; kk++) {
      const float4 a = *(const float4*)&Xa[kk][ty * 4];
      const float4 b = *(const float4*)&Xb[kk][tx * 4];
      FMA16(c, a, b)
    }
  }
#pragma unroll
  for (int ii = 0; ii < 4; ii++) {
    *(float4*)(G + (bi * 64 + ty * 4 + ii) * 1024 + bj * 64 + tx * 4) =
        make_float4(c[ii][0], c[ii][1], c[ii][2], c[ii][3]);
  }
}

// ----------------------------------------------------------------- k_z10 ----
__global__ __launch_bounds__(256) void k_z10(const float* __restrict__ X,
                                             const float* __restrict__ W1g,
                                             float* __restrict__ Z10) {
  const int bi = blockIdx.y, bj = blockIdx.x;
  __shared__ float At[32][68];
  __shared__ float Bt[32][68];
  const int tid = threadIdx.x;
  const int tx = tid & 15, ty = tid >> 4;
  float c[4][4] = {};
  for (int k0 = 0; k0 < 1024; k0 += 32) {
    __syncthreads();
    {
      const int row = tid >> 2, kk = (tid & 3) * 8;
      const float* pa = X + (bi * 64 + row) * 1024 + k0 + kk;
      const float4 a0 = *(const float4*)pa;
      const float4 a1 = *(const float4*)(pa + 4);
      At[kk + 0][row] = a0.x; At[kk + 1][row] = a0.y;
      At[kk + 2][row] = a0.z; At[kk + 3][row] = a0.w;
      At[kk + 4][row] = a1.x; At[kk + 5][row] = a1.y;
      At[kk + 6][row] = a1.z; At[kk + 7][row] = a1.w;
      const int kr = tid >> 3, j8 = (tid & 7) * 8;
      const float* pb = W1g + (k0 + kr) * 256 + bj * 64 + j8;
      *(float4*)&Bt[kr][j8]     = *(const float4*)pb;
      *(float4*)&Bt[kr][j8 + 4] = *(const float4*)(pb + 4);
    }
    __syncthreads();
#pragma unroll
    for (int kk = 0; kk < 32; kk++) {
      const float4 a = *(const float4*)&At[kk][ty * 4];
      const float4 b = *(const float4*)&Bt[kk][tx * 4];
      FMA16(c, a, b)
    }
  }
#pragma unroll
  for (int ii = 0; ii < 4; ii++) {
    *(float4*)(Z10 + (bi * 64 + ty * 4 + ii) * 256 + bj * 64 + tx * 4) =
        make_float4(c[ii][0], c[ii][1], c[ii][2], c[ii][3]);
  }
}

// --------------------------------------------------------------- k_w1out ----
__global__ __launch_bounds__(256) void k_w1out(
    const float* __restrict__ X, const float* __restrict__ o1g,
    const float* __restrict__ cg, const float* __restrict__ W1g,
    const float* __restrict__ sclg, float* __restrict__ outW1) {
  const int bi = blockIdx.y, bj = blockIdx.x;
  __shared__ float At[32][68];
  __shared__ float Bt[32][68];
  const int tid = threadIdx.x;
  const int tx = tid & 15, ty = tid >> 4;
  float c[4][4] = {};
  for (int k0 = 0; k0 < 1024; k0 += 32) {
    __syncthreads();
    {
      const int kr = tid >> 3, m8 = (tid & 7) * 8;
      const float* pa = X + (k0 + kr) * 1024 + bi * 64 + m8;
      *(float4*)&At[kr][m8]     = *(const float4*)pa;
      *(float4*)&At[kr][m8 + 4] = *(const float4*)(pa + 4);
      const float cs = cg[k0 + kr];
      const float* pb = o1g + (k0 + kr) * 256 + bj * 64 + m8;
      float4 b0 = *(const float4*)pb;
      float4 b1 = *(const float4*)(pb + 4);
      b0.x *= cs; b0.y *= cs; b0.z *= cs; b0.w *= cs;
      b1.x *= cs; b1.y *= cs; b1.z *= cs; b1.w *= cs;
      *(float4*)&Bt[kr][m8]     = b0;
      *(float4*)&Bt[kr][m8 + 4] = b1;
    }
    __syncthreads();
#pragma unroll
    for (int kk = 0; kk < 32; kk++) {
      const float4 a = *(const float4*)&At[kk][ty * 4];
      const float4 b = *(const float4*)&Bt[kk][tx * 4];
      FMA16(c, a, b)
    }
  }
  const float s1f = sclg[0];
#pragma unroll
  for (int ii = 0; ii < 4; ii++) {
    const int row = bi * 64 + ty * 4 + ii;
    const float4 w = *(const float4*)(W1g + row * 256 + bj * 64 + tx * 4);
    *(float4*)(outW1 + row * 256 + bj * 64 + tx * 4) =
        make_float4(s1f * (w.x + c[ii][0]), s1f * (w.y + c[ii][1]),
                    s1f * (w.z + c[ii][2]), s1f * (w.w + c[ii][3]));
  }
}

// ---------------------------------------------------------------- k2_seq ----
__device__ __forceinline__ float block_reduce8(float v, float* tmp, int tid) {
  v = wave_allred(v);
  __syncthreads();
  if ((tid & 63) == 0) tmp[tid >> 6] = v;
  __syncthreads();
  float s = 0.f;
#pragma unroll
  for (int w = 0; w < 8; w++) s += tmp[w];
  __syncthreads();
  return s;
}

__global__ __launch_bounds__(512, 1) void k2_seq(
    const float* __restrict__ Tg, const float* __restrict__ W1g,
    const float* __restrict__ b1g, const float* __restrict__ W2g,
    const float* __restrict__ b2g, const float* __restrict__ W3g,
    const float* __restrict__ b3g, const float* __restrict__ G,
    const float* __restrict__ Z10, float* __restrict__ o1g,
    float* __restrict__ cg, float* __restrict__ sclg,
    float* __restrict__ outW2, float* __restrict__ outW3) {
  extern __shared__ float sm[];
  float* const zo   = sm;            // [64][272]: z1p row l until step l, then o1
  float* const Gb   = sm + 17408;    // [64][64] plain / [64][33] prefix staging
  float* const scr  = sm + 21504;    // 8448: prefix staging / B1 [16][264] / C1 [16][130]
  float* const Tb   = sm + 29952;    // [64][64] targets for this block
  float* const a1v  = sm + 34048;    // [2][256] double-buffered by step parity
  float* const z1v  = sm + 34560;    // 256 (z1u, for dts0)
  float* const z2v  = sm + 34816;    // 256 (physical z2)
  float* const a2v  = sm + 35072;    // 256
  float* const o2v  = sm + 35328;    // 256
  float* const b1ps = sm + 35584;    // 256 (pre-norm physical b1)
  float* const b2ps = sm + 35840;    // 256
  float* const d3v  = sm + 36096;    // 64
  float* const b3ps = sm + 36160;    // [2][64] parity-buffered pre-norm b3
  float* const ch   = sm + 36288;    // 64  in-block c coefficients
  float* const dpart= sm + 36352;    // 72  dot wave-partials (16B aligned)
  float* const cpre = sm + 36424;    // 32

  const int tid = threadIdx.x;
  const int lane = tid & 63;
  const int w = tid >> 6;            // wave 0..7
  const int p = tid >> 5;            // 0..15 : 16-row group
  const int q = tid & 31;            // 0..31 : 8-col group (W2) / 2-col (W3)
  const int gl = lane & 31;          // group-local lane (half-wave)
  const bool bt1 = (lane & 1), bt2 = (lane & 2), bt4 = (lane & 4),
             bt8 = (lane & 8);

  // ---- persistent per-thread state as named SSA values (no arrays!) ----
  // W2_phys = s2 * R2 ; W3_phys = s3 * R3  (lazy scales)
  f32x8 W2_0, W2_1, W2_2, W2_3, W2_4, W2_5, W2_6, W2_7,
        W2_8, W2_9, W2_10, W2_11, W2_12, W2_13, W2_14, W2_15;
  float W3x_0, W3x_1, W3x_2, W3x_3, W3x_4, W3x_5, W3x_6, W3x_7,
        W3x_8, W3x_9, W3x_10, W3x_11, W3x_12, W3x_13, W3x_14, W3x_15;
  float W3y_0, W3y_1, W3y_2, W3y_3, W3y_4, W3y_5, W3y_6, W3y_7,
        W3y_8, W3y_9, W3y_10, W3y_11, W3y_12, W3y_13, W3y_14, W3y_15;

#define INIT_ROW(i)                                                           \
  { const int row = p * 16 + i;                                               \
    W2_##i  = *(const f32x8*)(W2g + row * 256 + q * 8);                       \
    W3x_##i = W3g[row * 64 + q * 2];                                          \
    W3y_##i = W3g[row * 64 + q * 2 + 1]; }
  ROWS16(INIT_ROW)

  if (tid < 256) { b1ps[tid] = b1g[tid]; b2ps[tid] = b2g[tid]; }
  if (tid < 64) b3ps[tid] = b3g[tid];

  // Initial squared norms (broadcast to all threads).
  float acc1 = 0.f;
  for (int i = tid; i < 65536; i += 512) {
    const float4 v = ((const float4*)W1g)[i];
    acc1 += v.x * v.x + v.y * v.y + v.z * v.z + v.w * v.w;
  }
  const float n1init = block_reduce8(acc1, scr, tid);
  float acc2 = 0.f;
#define N2_ROW(i) { f32x8 t = W2_##i * W2_##i; acc2 += hsum8(t); }
  ROWS16(N2_ROW)
  const float n2init = block_reduce8(acc2, scr, tid);
  float acc3 = 0.f;
#define N3_ROW(i) acc3 += W3x_##i * W3x_##i + W3y_##i * W3y_##i;
  ROWS16(N3_ROW)
  const float n3init = block_reduce8(acc3, scr, tid);

  // Replicated scalar recurrence state (bitwise identical on all threads:
  // same LDS inputs, same op sequence).
  float s1 = 1.f, s2 = 1.f, s3 = 1.f;
  float rb1 = 1.f, rb2 = 1.f, rb3 = 1.f;
  float c1r = 0.f, cw2r = 0.f, cw3r = 0.f;
  double n1d = (double)n1init;
  float n2 = n2init, n3 = n3init;
  __syncthreads();

  // Scalar chain for the step whose in-block index is lidx (inputs in dpart;
  // pv3 = parity offset of that step's |a1|^2 slots).
  auto run_chain = [&](const int lidx, const int pv3) {
    const float4 qa0 = *(const float4*)&dpart[0];
    const float4 qa1 = *(const float4*)&dpart[4];
    const float4 qb0 = *(const float4*)&dpart[8];
    const float4 qb1 = *(const float4*)&dpart[12];
    const float4 qc0 = *(const float4*)&dpart[16];
    const float4 qc1 = *(const float4*)&dpart[20];
    const float4 qd0 = *(const float4*)&dpart[24];
    const float4 qd1 = *(const float4*)&dpart[28];
    const float4 qe0 = *(const float4*)&dpart[32];
    const float4 qe1 = *(const float4*)&dpart[36];
    const float4 qf0 = *(const float4*)&dpart[40];
    const float4 qf1 = *(const float4*)&dpart[44];
    const float4 qg0 = *(const float4*)&dpart[48 + pv3];
    const float4 qg1 = *(const float4*)&dpart[52 + pv3];
    const float4 qh  = *(const float4*)&dpart[64];
    const float4 qi  = *(const float4*)&dpart[68];
#define SUM8(x0, x1) (((x0.x + x0.y) + (x0.z + x0.w)) +                       \
                      ((x1.x + x1.y) + (x1.z + x1.w)))
    const float dts0 = SUM8(qa0, qa1);
    const float dts1 = SUM8(qb0, qb1);
    const float dts8 = SUM8(qc0, qc1);
    const float dts2 = SUM8(qd0, qd1);
    const float dts4 = SUM8(qe0, qe1);
    const float dts9 = SUM8(qf0, qf1);
    const float dts3 = SUM8(qg0, qg1);
    const float dts5 = qh.x, dts7 = qh.y, dts10 = qh.z;
    const float dts6 = (qi.x + qi.y) + (qi.z + qi.w);
    const float c1 = -LRC / s1;
    c1r = c1; cw2r = -LRC / s2; cw3r = -LRC / s3;
    const double gtt = (double)Gb[lidx * 65];
    n1d = n1d + 2.0 * (double)c1 * (double)dts0 +
          (double)c1 * (double)c1 * gtt * (double)dts1;
    const double w1n = (double)s1 * sqrt(n1d);
    s1 = (float)((double)s1 / fmax(w1n, (double)EPSV));
    rb1 = 1.f / fmaxf(sqrtf(dts8), EPSV);
    const float n2p = n2 - 2.f * LRC * dts2 + LRC * LRC * dts3 * dts4;
    const float r2s = 1.f / fmaxf(sqrtf(n2p), EPSV);
    n2 = n2p * r2s * r2s;
    s2 = s2 * r2s;
    rb2 = 1.f / fmaxf(sqrtf(dts9), EPSV);
    const float n3p = n3 - 2.f * LRC * dts5 + LRC * LRC * dts6 * dts7;
    const float r3s = 1.f / fmaxf(sqrtf(n3p), EPSV);
    n3 = n3p * r3s * r3s;
    s3 = s3 * r3s;
    rb3 = 1.f / fmaxf(sqrtf(dts10), EPSV);
    if (tid == 0) ch[lidx] = c1;
  };

  for (int b = 0; b < 16; b++) {
    const int bs = b * 64;
    // ---- prefix: zo[row][j] = Z10[bs+row][j] + sum_{s<bs} cg[s]G[bs+row][s]o1[s][j]
    {
      f32x8 pacc0 = {0.f, 0.f, 0.f, 0.f, 0.f, 0.f, 0.f, 0.f};
      f32x8 pacc1 = pacc0, pacc2 = pacc0, pacc3 = pacc0;
      for (int c0 = 0; c0 < bs; c0 += 32) {
        __syncthreads();
        if (tid < 32) cpre[tid] = cg[c0 + tid];
        {
          const int row = tid >> 3, k4 = (tid & 7) * 4;
          const float4 gv = *(const float4*)(G + (bs + row) * 1024 + c0 + k4);
          Gb[row * 33 + k4 + 0] = gv.x; Gb[row * 33 + k4 + 1] = gv.y;
          Gb[row * 33 + k4 + 2] = gv.z; Gb[row * 33 + k4 + 3] = gv.w;
        }
#pragma unroll
        for (int u = 0; u < 4; u++) {
          const int fi = tid + u * 512;
          ((float4*)scr)[fi] = ((const float4*)(o1g + c0 * 256))[fi];
        }
        __syncthreads();
#pragma unroll 2
        for (int ss = 0; ss < 32; ss++) {
          const float cs = cpre[ss];
          const f32x8 o8 = *(const f32x8*)(scr + ss * 256 + q * 8);
          pacc0 += (Gb[(p * 4 + 0) * 33 + ss] * cs) * o8;
          pacc1 += (Gb[(p * 4 + 1) * 33 + ss] * cs) * o8;
          pacc2 += (Gb[(p * 4 + 2) * 33 + ss] * cs) * o8;
          pacc3 += (Gb[(p * 4 + 3) * 33 + ss] * cs) * o8;
        }
      }
      __syncthreads();
#define ZSTORE(rr)                                                            \
      { const int row = p * 4 + rr;                                           \
        *(f32x8*)(zo + row * 272 + q * 8) =                                   \
            *(const f32x8*)(Z10 + (bs + row) * 256 + q * 8) + pacc##rr; }
      ZSTORE(0) ZSTORE(1) ZSTORE(2) ZSTORE(3)
      // this block's 64x64 Gram square (plain layout) + targets
#pragma unroll
      for (int u = 0; u < 2; u++) {
        const int fi = tid + u * 512;
        const int row = fi >> 4, c4 = fi & 15;
        *(float4*)(Gb + row * 64 + c4 * 4) =
            *(const float4*)(G + (bs + row) * 1024 + bs + c4 * 4);
      }
      ((float4*)Tb)[tid]       = ((const float4*)(Tg + bs * 64))[tid];
      ((float4*)Tb)[tid + 512] = ((const float4*)(Tg + bs * 64))[tid + 512];
      __syncthreads();
    }

    // ---- 64 sequential steps, 6 barrier-fenced phases each
    for (int l = 0; l < 64; l++) {
      const int t = bs + l;
      const int cur = (t & 1) * 256, prv = 256 - cur;

      // ======== Phase A: chain + deferred update + history + a1 ==========
      if (l > 0) run_chain(l - 1, ((t - 1) & 1) * 8);
      if (t > 0) {
        const f32x8 o8s = cw2r * (*(const f32x8*)&o2v[q * 8]);
        const float d0s = cw3r * d3v[q * 2], d1s = cw3r * d3v[q * 2 + 1];
#define UPD_ROW(i)                                                            \
        { const float a1o = a1v[prv + p * 16 + i];                            \
          W2_##i += a1o * o8s;                                                \
          const float a2o = a2v[p * 16 + i];                                  \
          W3x_##i += a2o * d0s; W3y_##i += a2o * d1s; }
        ROWS16(UPD_ROW)
      }
      {
        const int jp = tid >> 2, quarter = tid & 3;   // j-pair {2jp, 2jp+1}
        float ax = 0.f, ay = 0.f;
        for (int lp = quarter; lp < l - 1; lp += 4) {
          const float gcs = ch[lp] * Gb[l * 64 + lp];
          const float2 zr = *(const float2*)&zo[lp * 272 + 2 * jp];
          ax += gcs * zr.x; ay += gcs * zr.y;
        }
        if (l > 0 && ((l - 1) & 3) == quarter) {   // newest term via register
          const float gcs = c1r * Gb[l * 64 + (l - 1)];
          const float2 zr = *(const float2*)&zo[(l - 1) * 272 + 2 * jp];
          ax += gcs * zr.x; ay += gcs * zr.y;
        }
        ax = dpp_add<0xB1>(ax); ax = dpp_add<0x4E>(ax);
        ay = dpp_add<0xB1>(ay); ay = dpp_add<0x4E>(ay);
        const float2 zop = *(const float2*)&zo[l * 272 + 2 * jp];
        const float2 b1q = *(const float2*)&b1ps[2 * jp];
        const float z1u0 = zop.x + ax, z1u1 = zop.y + ay;
        const float a1x0 = 1.f / (1.f + expf(-(s1 * z1u0 + rb1 * b1q.x)));
        const float a1x1 = 1.f / (1.f + expf(-(s1 * z1u1 + rb1 * b1q.y)));
        if (quarter == 0) {
          *(float2*)&z1v[2 * jp] = make_float2(z1u0, z1u1);
          *(float2*)&a1v[cur + 2 * jp] = make_float2(a1x0, a1x1);
        }
        const float v3 = dpp_allred64(
            quarter == 0 ? a1x0 * a1x0 + a1x1 * a1x1 : 0.f);
        if (lane == 0) dpart[48 + (t & 1) * 8 + w] = v3;
      }
      __syncthreads();

      // ======== Phase B1: z2 partials = a1 @ R2 ==========================
      {
        f32x8 acc = {0.f, 0.f, 0.f, 0.f, 0.f, 0.f, 0.f, 0.f};
#define B1_ROW(i) acc += a1v[cur + p * 16 + i] * W2_##i;
        ROWS16(B1_ROW)
        *(f32x8*)&scr[p * 264 + q * 8] = acc;
      }
      __syncthreads();

      // ======== Phase B2: z2 reduce, a2, |a2|² dot =======================
      if (tid < 256) {
        float s = 0.f;
#pragma unroll
        for (int pp = 0; pp < 16; pp++) s += scr[pp * 264 + tid];
        const float z2p = s2 * s;
        z2v[tid] = z2p;
        const float a2x = 1.f / (1.f + expf(-(z2p + rb2 * b2ps[tid])));
        a2v[tid] = a2x;
        const float v6w = dpp_allred64(a2x * a2x);
        if ((tid & 63) == 0) dpart[68 + (tid >> 6)] = v6w;
      }
      __syncthreads();

      // ======== Phase C1: z3 partials (transposed float2 layout) =========
      {
        float c0a = 0.f, c1a = 0.f;
#define C1_ROW(i)                                                             \
        { const float a2x = a2v[p * 16 + i];                                  \
          c0a += a2x * W3x_##i; c1a += a2x * W3y_##i; }
        ROWS16(C1_ROW)
        *(float2*)&scr[p * 130 + 2 * q] = make_float2(c0a, c1a);
      }
      __syncthreads();

      // ======== Phase CE: softmax/d3/b3 (per-half-wave) + o2 tree + b2 ===
      {
        float z30 = 0.f, z31 = 0.f;
#pragma unroll
        for (int pp = 0; pp < 16; pp++) {
          const float2 zz = *(const float2*)&scr[pp * 130 + 2 * q];
          z30 += zz.x; z31 += zz.y;
        }
        const float z3p0 = s3 * z30, z3p1 = s3 * z31;
        const int pbR = (t & 1) * 64, pbW = 64 - pbR;
        const float b3o0 = b3ps[pbR + 2 * q], b3o1 = b3ps[pbR + 2 * q + 1];
        const float a30 = 1.f / (1.f + expf(-(z3p0 + rb3 * b3o0)));
        const float a31 = 1.f / (1.f + expf(-(z3p1 + rb3 * b3o1)));
        const float e0 = expf(-a30), e1 = expf(-a31);
        const float tot2 = dpp_allred64(e0 + e1);   // 2 × Σe (halves duplicate)
        const float out0 = (2.f * e0) / tot2, out1 = (2.f * e1) / tot2;
        const float2 tb = *(const float2*)&Tb[l * 64 + 2 * q];
        const float d30 = (tb.x - out0) * a30 * (1.f - a30);
        const float d31 = (tb.y - out1) * a31 * (1.f - a31);
        const float b3n0 = rb3 * b3o0 - LRC * d30;
        const float b3n1 = rb3 * b3o1 - LRC * d31;
        if (tid < 32) {
          d3v[2 * q] = d30; d3v[2 * q + 1] = d31;
          b3ps[pbW + 2 * q] = b3n0; b3ps[pbW + 2 * q + 1] = b3n1;
        }
        const float v5w = dpp_allred64(z3p0 * d30 + z3p1 * d31);
        const float v7w = dpp_allred64(d30 * d30 + d31 * d31);
        const float v10w = dpp_allred64(b3n0 * b3n0 + b3n1 * b3n1);
        if (tid == 0) {
          dpart[64] = 0.5f * v5w; dpart[65] = 0.5f * v7w;
          dpart[66] = 0.5f * v10w;
        }
        // o2 via in-group tree: v[i] = Σ_{j∈{2q,2q+1}} W3[16p+i][j]·d3_j
        float v[16];
#define CE_ROW(i) v[i] = W3x_##i * d30 + W3y_##i * d31;
        ROWS16(CE_ROW)
        TREE16()
        const int r = p * 16 + (gl & 15);
        const float a2x = a2v[r];
        const float o2x = s3 * v[0] * a2x * (1.f - a2x);
        const float z2x = z2v[r];
        const float b2o = b2ps[r];
        const float b2n = rb2 * b2o - LRC * o2x;
        if (gl < 16) { o2v[r] = o2x; b2ps[r] = b2n; }
        const bool own = gl < 16;
        const float v2w = dpp_allred64(own ? z2x * o2x : 0.f);
        const float v4w = dpp_allred64(own ? o2x * o2x : 0.f);
        const float v9w = dpp_allred64(own ? b2n * b2n : 0.f);
        if (lane == 0) {
          dpart[24 + w] = v2w; dpart[32 + w] = v4w; dpart[40 + w] = v9w;
        }
      }
      __syncthreads();

      // ======== Phase F: o1 = R2 @ o2 via tree + zo/b1 + dots ============
      {
        const f32x8 ov8 = *(const f32x8*)&o2v[q * 8];
        float v[16];
#define F_ROW(i) { f32x8 tq = W2_##i * ov8; v[i] = hsum8(tq); }
        ROWS16(F_ROW)
        TREE16()
        const int r = p * 16 + (gl & 15);
        const float a1x = a1v[cur + r];
        const float o1x = s2 * v[0] * a1x * (1.f - a1x);
        const float b1o = b1ps[r];
        const float b1n = rb1 * b1o - LRC * o1x;
        const float z1x = z1v[r];
        if (gl < 16) { zo[l * 272 + r] = o1x; b1ps[r] = b1n; }
        const bool own = gl < 16;
        const float v0w = dpp_allred64(own ? z1x * o1x : 0.f);
        const float v1w = dpp_allred64(own ? o1x * o1x : 0.f);
        const float v8w = dpp_allred64(own ? b1n * b1n : 0.f);
        if (lane == 0) {
          dpart[0 + w] = v0w; dpart[8 + w] = v1w; dpart[16 + w] = v8w;
        }
      }
      __syncthreads();
    }

    // ---- tail: scalar chain for step bs+63 (before flush needs ch[63])
    run_chain(63, ((bs + 63) & 1) * 8);
    __syncthreads();

    // ---- per-block flush of o1 (from zo) and c (from ch) to global
    {
#pragma unroll
      for (int u = 0; u < 4; u++) {
        const int chunk = tid + u * 512;          // 0..2047
        const int row = chunk >> 5, c8 = chunk & 31;
        *(f32x8*)(o1g + (bs + row) * 256 + c8 * 8) =
            *(const f32x8*)(zo + row * 272 + c8 * 8);
      }
      if (tid < 64) cg[bs + tid] = ch[tid];
    }
    // next block's prefix __syncthreads() drains these stores before reads
  }

  // ---- epilogue: apply deferred update of step 1023, write scaled outputs
  {
    const f32x8 o8s = cw2r * (*(const f32x8*)&o2v[q * 8]);
    const float d0s = cw3r * d3v[q * 2], d1s = cw3r * d3v[q * 2 + 1];
#define FIN_ROW(i)                                                            \
    { const float a1o = a1v[256 + p * 16 + i]; /* parity of t=1023 */         \
      W2_##i += a1o * o8s;                                                    \
      const float a2o = a2v[p * 16 + i];                                      \
      W3x_##i += a2o * d0s; W3y_##i += a2o * d1s;                             \
      const int row = p * 16 + i;                                             \
      *(f32x8*)(outW2 + row * 256 + q * 8) = s2 * W2_##i;                     \
      outW3[row * 64 + q * 2]     = s3 * W3x_##i;                             \
      outW3[row * 64 + q * 2 + 1] = s3 * W3y_##i; }
    ROWS16(FIN_ROW)
    if (tid == 0) sclg[0] = s1;
  }
}

// ---------------------------------------------------------------- launch ----
extern "C" void kernel_launch(void* const* d_in, const int* in_sizes, int n_in,
                              void* d_out, int out_size, void* d_ws,
                              size_t ws_size, hipStream_t stream) {
  (void)in_sizes; (void)n_in; (void)out_size; (void)ws_size;
  const float* X   = (const float*)d_in[0];
  const float* Tg  = (const float*)d_in[1];
  const float* W1g = (const float*)d_in[2];
  const float* b1g = (const float*)d_in[3];
  const float* W2g = (const float*)d_in[4];
  const float* b2g = (const float*)d_in[5];
  const float* W3g = (const float*)d_in[6];
  const float* b3g = (const float*)d_in[7];
  float* out = (float*)d_out;
  float* ws  = (float*)d_ws;

  float* G    = ws;
  float* Z10  = G + 1048576;
  float* o1g  = Z10 + 262144;
  float* cg   = o1g + 262144;
  float* sclg = cg + 1024;

  (void)hipFuncSetAttribute((const void*)k2_seq,
                            hipFuncAttributeMaxDynamicSharedMemorySize,
                            SMEM_BYTES);

  k_gram<<<dim3(16, 16), 256, 0, stream>>>(X, G);
  k_z10<<<dim3(4, 16), 256, 0, stream>>>(X, W1g, Z10);
  k2_seq<<<dim3(1), dim3(512), SMEM_BYTES, stream>>>(
      Tg, W1g, b1g, W2g, b2g, W3g, b3g, G, Z10, o1g, cg, sclg,
      out + 262144, out + 327680);
  k_w1out<<<dim3(4, 16), 256, 0, stream>>>(X, o1g, cg, W1g, sclg, out);
}

// Round 5
// 8657.446 us; speedup vs baseline: 1.2195x; 1.2195x over previous
//
#include <hip/hip_runtime.h>
#include <math.h>

// Backprop_29188597744223 — 1024-step sequential MLP training scan.
//
//   k_gram : G = X·Xᵀ (lower triangle + diag tiles), grid-parallel
//   k_z10  : Z10 = X·W1_init, grid-parallel
//   k2_seq : ONE workgroup, 512 threads (8 waves). 8 barrier-fenced phases:
//              A : W3 deferred update + z1 history (4-way, quad-DPP) + a1
//                  + |a1|² and a1·a1_prev dots
//              B1: z2 partials = a1 @ W2_old -> scr
//              B2: waves 0-3: z2 reduce + rank-1 correction
//                  (adot·cw2·o2_prev), a2, |a2|² dot; waves 4-7: W2 update
//              C1: z3 partials = a2 @ W3 -> scr
//              C2: wave 7: z3 reduce, softmax(-a3), d3, b3, d3-dots;
//                  waves 0-3: W2 update; waves 4-6 idle
//              E : o2 partials (all) | lgkmcnt fence | intra-wave reduce —
//                  wave w owns rows 32w..+31 (writers of those rows ARE
//                  wave w) -> o2, b2, dots.  (E1+E2 merged, no barrier)
//              F : o1 partials | fence | intra-wave reduce -> zo, b1, dots
//              H : wave 0: f64 n1 chain, s1, rb1, ch; wave 7: n2/n3 chains,
//                  s2/s3/rb2/rb3/cw2/cw3 -> sca  (parallel waves)
//            W2: thread (p,q) owns rows 16p..+15 × cols 8q..+7 (16 f32x8).
//            W3: same thread owns rows 16p..+15 × cols 2q..+1 (32 scalars).
//            Lazy scales s2/s3; biases pre-norm with rb folded at use; no
//            global stores in the step loop (o1/c flushed per 64-step block).
//   k_w1out: W1_final = s1_f·(W1_init + Xᵀ·diag(c)·O1), grid-parallel

#define LRC  0.01f
#define EPSV 1e-8f

typedef float f32x8 __attribute__((ext_vector_type(8)));

#define SMEM_FLOATS 36400
#define SMEM_BYTES  (SMEM_FLOATS * 4)

#define ROWS16(OP)                                                            \
  OP(0) OP(1) OP(2) OP(3) OP(4) OP(5) OP(6) OP(7)                             \
  OP(8) OP(9) OP(10) OP(11) OP(12) OP(13) OP(14) OP(15)

__device__ __forceinline__ float hsum8(f32x8 v) {
  return ((v.s0 + v.s1) + (v.s2 + v.s3)) + ((v.s4 + v.s5) + (v.s6 + v.s7));
}

// ---- DPP reductions (VALU-rate; no DS pipe) --------------------------------
template <int CTRL>
__device__ __forceinline__ float dpp_add(float v) {
  const int s = __builtin_amdgcn_update_dpp(0, __builtin_bit_cast(int, v),
                                            CTRL, 0xf, 0xf, true);
  return v + __builtin_bit_cast(float, s);
}

// Full 64-lane sum, result broadcast to all lanes via readlane(63).
__device__ __forceinline__ float dpp_allred64(float v) {
  v = dpp_add<0x111>(v);   // row_shr:1
  v = dpp_add<0x112>(v);   // row_shr:2
  v = dpp_add<0x114>(v);   // row_shr:4
  v = dpp_add<0x118>(v);   // row_shr:8  -> lane15/31/47/63 hold row sums
  v = dpp_add<0x142>(v);   // row_bcast:15
  v = dpp_add<0x143>(v);   // row_bcast:31 -> lane 63 holds total
  return __builtin_bit_cast(float,
      __builtin_amdgcn_readlane(__builtin_bit_cast(int, v), 63));
}

__device__ __forceinline__ float wave_allred(float v) {  // init-path only
#pragma unroll
  for (int off = 32; off > 0; off >>= 1) v += __shfl_xor(v, off);
  return v;
}

// In-wave fence: order own-wave LDS writes -> LDS reads without s_barrier.
__device__ __forceinline__ void wave_fence() {
  __builtin_amdgcn_sched_barrier(0);
  asm volatile("s_waitcnt lgkmcnt(0)" ::: "memory");
  __builtin_amdgcn_sched_barrier(0);
}

#define FMA16(c, a, b)                                                        \
  c[0][0] += a.x * b.x; c[0][1] += a.x * b.y; c[0][2] += a.x * b.z; c[0][3] += a.x * b.w; \
  c[1][0] += a.y * b.x; c[1][1] += a.y * b.y; c[1][2] += a.y * b.z; c[1][3] += a.y * b.w; \
  c[2][0] += a.z * b.x; c[2][1] += a.z * b.y; c[2][2] += a.z * b.z; c[2][3] += a.z * b.w; \
  c[3][0] += a.w * b.x; c[3][1] += a.w * b.y; c[3][2] += a.w * b.z; c[3][3] += a.w * b.w;

// ---------------------------------------------------------------- k_gram ----
__global__ __launch_bounds__(256) void k_gram(const float* __restrict__ X,
                                              float* __restrict__ G) {
  const int bi = blockIdx.y, bj = blockIdx.x;
  if (bj > bi) return;
  __shared__ float Xa[32][68];
  __shared__ float Xb[32][68];
  const int tid = threadIdx.x;
  const int tx = tid & 15, ty = tid >> 4;
  float c[4][4] = {};
  for (int k0 = 0; k0 < 1024; k0 += 32) {
    __syncthreads();
    {
      const int row = tid >> 2, kk = (tid & 3) * 8;
      const float* pa = X + (bi * 64 + row) * 1024 + k0 + kk;
      const float4 a0 = *(const float4*)pa;
      const float4 a1 = *(const float4*)(pa + 4);
      Xa[kk + 0][row] = a0.x; Xa[kk + 1][row] = a0.y;
      Xa[kk + 2][row] = a0.z; Xa[kk + 3][row] = a0.w;
      Xa[kk + 4][row] = a1.x; Xa[kk + 5][row] = a1.y;
      Xa[kk + 6][row] = a1.z; Xa[kk + 7][row] = a1.w;
      const float* pb = X + (bj * 64 + row) * 1024 + k0 + kk;
      const float4 b0 = *(const float4*)pb;
      const float4 b1 = *(const float4*)(pb + 4);
      Xb[kk + 0][row] = b0.x; Xb[kk + 1][row] = b0.y;
      Xb[kk + 2][row] = b0.z; Xb[kk + 3][row] = b0.w;
      Xb[kk + 4][row] = b1.x; Xb[kk + 5][row] = b1.y;
      Xb[kk + 6][row] = b1.z; Xb[kk + 7][row] = b1.w;
    }
    __syncthreads();
#pragma unroll
    for (int kk = 0; kk < 32; kk++) {
      const float4 a = *(const float4*)&Xa[kk][ty * 4];
      const float4 b = *(const float4*)&Xb[kk][tx * 4];
      FMA16(c, a, b)
    }
  }
#pragma unroll
  for (int ii = 0; ii < 4; ii++) {
    *(float4*)(G + (bi * 64 + ty * 4 + ii) * 1024 + bj * 64 + tx * 4) =
        make_float4(c[ii][0], c[ii][1], c[ii][2], c[ii][3]);
  }
}

// ----------------------------------------------------------------- k_z10 ----
__global__ __launch_bounds__(256) void k_z10(const float* __restrict__ X,
                                             const float* __restrict__ W1g,
                                             float* __restrict__ Z10) {
  const int bi = blockIdx.y, bj = blockIdx.x;
  __shared__ float At[32][68];
  __shared__ float Bt[32][68];
  const int tid = threadIdx.x;
  const int tx = tid & 15, ty = tid >> 4;
  float c[4][4] = {};
  for (int k0 = 0; k0 < 1024; k0 += 32) {
    __syncthreads();
    {
      const int row = tid >> 2, kk = (tid & 3) * 8;
      const float* pa = X + (bi * 64 + row) * 1024 + k0 + kk;
      const float4 a0 = *(const float4*)pa;
      const float4 a1 = *(const float4*)(pa + 4);
      At[kk + 0][row] = a0.x; At[kk + 1][row] = a0.y;
      At[kk + 2][row] = a0.z; At[kk + 3][row] = a0.w;
      At[kk + 4][row] = a1.x; At[kk + 5][row] = a1.y;
      At[kk + 6][row] = a1.z; At[kk + 7][row] = a1.w;
      const int kr = tid >> 3, j8 = (tid & 7) * 8;
      const float* pb = W1g + (k0 + kr) * 256 + bj * 64 + j8;
      *(float4*)&Bt[kr][j8]     = *(const float4*)pb;
      *(float4*)&Bt[kr][j8 + 4] = *(const float4*)(pb + 4);
    }
    __syncthreads();
#pragma unroll
    for (int kk = 0; kk < 32; kk++) {
      const float4 a = *(const float4*)&At[kk][ty * 4];
      const float4 b = *(const float4*)&Bt[kk][tx * 4];
      FMA16(c, a, b)
    }
  }
#pragma unroll
  for (int ii = 0; ii < 4; ii++) {
    *(float4*)(Z10 + (bi * 64 + ty * 4 + ii) * 256 + bj * 64 + tx * 4) =
        make_float4(c[ii][0], c[ii][1], c[ii][2], c[ii][3]);
  }
}

// --------------------------------------------------------------- k_w1out ----
__global__ __launch_bounds__(256) void k_w1out(
    const float* __restrict__ X, const float* __restrict__ o1g,
    const float* __restrict__ cg, const float* __restrict__ W1g,
    const float* __restrict__ sclg, float* __restrict__ outW1) {
  const int bi = blockIdx.y, bj = blockIdx.x;
  __shared__ float At[32][68];
  __shared__ float Bt[32][68];
  const int tid = threadIdx.x;
  const int tx = tid & 15, ty = tid >> 4;
  float c[4][4] = {};
  for (int k0 = 0; k0 < 1024; k0 += 32) {
    __syncthreads();
    {
      const int kr = tid >> 3, m8 = (tid & 7) * 8;
      const float* pa = X + (k0 + kr) * 1024 + bi * 64 + m8;
      *(float4*)&At[kr][m8]     = *(const float4*)pa;
      *(float4*)&At[kr][m8 + 4] = *(const float4*)(pa + 4);
      const float cs = cg[k0 + kr];
      const float* pb = o1g + (k0 + kr) * 256 + bj * 64 + m8;
      float4 b0 = *(const float4*)pb;
      float4 b1 = *(const float4*)(pb + 4);
      b0.x *= cs; b0.y *= cs; b0.z *= cs; b0.w *= cs;
      b1.x *= cs; b1.y *= cs; b1.z *= cs; b1.w *= cs;
      *(float4*)&Bt[kr][m8]     = b0;
      *(float4*)&Bt[kr][m8 + 4] = b1;
    }
    __syncthreads();
#pragma unroll
    for (int kk = 0; kk < 32; kk++) {
      const float4 a = *(const float4*)&At[kk][ty * 4];
      const float4 b = *(const float4*)&Bt[kk][tx * 4];
      FMA16(c, a, b)
    }
  }
  const float s1f = sclg[0];
#pragma unroll
  for (int ii = 0; ii < 4; ii++) {
    const int row = bi * 64 + ty * 4 + ii;
    const float4 w = *(const float4*)(W1g + row * 256 + bj * 64 + tx * 4);
    *(float4*)(outW1 + row * 256 + bj * 64 + tx * 4) =
        make_float4(s1f * (w.x + c[ii][0]), s1f * (w.y + c[ii][1]),
                    s1f * (w.z + c[ii][2]), s1f * (w.w + c[ii][3]));
  }
}

// ---------------------------------------------------------------- k2_seq ----
__device__ __forceinline__ float block_reduce8(float v, float* tmp, int tid) {
  v = wave_allred(v);
  __syncthreads();
  if ((tid & 63) == 0) tmp[tid >> 6] = v;
  __syncthreads();
  float s = 0.f;
#pragma unroll
  for (int w = 0; w < 8; w++) s += tmp[w];
  __syncthreads();
  return s;
}

__global__ __launch_bounds__(512, 1) void k2_seq(
    const float* __restrict__ Tg, const float* __restrict__ W1g,
    const float* __restrict__ b1g, const float* __restrict__ W2g,
    const float* __restrict__ b2g, const float* __restrict__ W3g,
    const float* __restrict__ b3g, const float* __restrict__ G,
    const float* __restrict__ Z10, float* __restrict__ o1g,
    float* __restrict__ cg, float* __restrict__ sclg,
    float* __restrict__ outW2, float* __restrict__ outW3) {
  extern __shared__ float sm[];
  float* const zo   = sm;            // [64][272]: z1p row l until step l, then o1
  float* const Gb   = sm + 17408;    // [64][64] plain / [64][33] prefix staging
  float* const scr  = sm + 21504;    // 8448 floats: partials / o1 staging
  float* const Tb   = sm + 29952;    // [64][64] targets for this block
  float* const a1v  = sm + 34048;    // [2][256] double-buffered by step parity
  float* const z1v  = sm + 34560;    // 256 (z1u, for dts0)
  float* const z2v  = sm + 34816;    // 256 (physical z2)
  float* const a2v  = sm + 35072;    // 256
  float* const o2v  = sm + 35328;    // 256
  float* const b1ps = sm + 35584;    // 256 (pre-norm physical b1)
  float* const b2ps = sm + 35840;    // 256
  float* const d3v  = sm + 36096;    // 64
  float* const b3ps = sm + 36160;    // 64
  float* const ch   = sm + 36224;    // 64  in-block c coefficients
  float* const dpart= sm + 36288;    // 72  dot wave-partials
  float* const sca  = sm + 36360;    // 8   {s1, rb1, s2, rb2, s3, rb3, cw2, cw3}
  float* const cpre = sm + 36368;    // 32

  const int tid = threadIdx.x;
  const int lane = tid & 63;
  const int w = tid >> 6;            // wave 0..7
  const int p = tid >> 5;            // 0..15 : 16-row group
  const int q = tid & 31;            // 0..31 : 8-col group (W2) / 2-col (W3)
  const int rown = 32 * w + (lane & 31);  // intra-wave reduce row (E/F)

  // ---- persistent per-thread state as named SSA values (no arrays!) ----
  // W2_phys = s2 * R2 ; W3_phys = s3 * R3  (lazy scales)
  f32x8 W2_0, W2_1, W2_2, W2_3, W2_4, W2_5, W2_6, W2_7,
        W2_8, W2_9, W2_10, W2_11, W2_12, W2_13, W2_14, W2_15;
  float W3x_0, W3x_1, W3x_2, W3x_3, W3x_4, W3x_5, W3x_6, W3x_7,
        W3x_8, W3x_9, W3x_10, W3x_11, W3x_12, W3x_13, W3x_14, W3x_15;
  float W3y_0, W3y_1, W3y_2, W3y_3, W3y_4, W3y_5, W3y_6, W3y_7,
        W3y_8, W3y_9, W3y_10, W3y_11, W3y_12, W3y_13, W3y_14, W3y_15;

#define INIT_ROW(i)                                                           \
  { const int row = p * 16 + i;                                               \
    W2_##i  = *(const f32x8*)(W2g + row * 256 + q * 8);                       \
    W3x_##i = W3g[row * 64 + q * 2];                                          \
    W3y_##i = W3g[row * 64 + q * 2 + 1]; }
  ROWS16(INIT_ROW)

  if (tid < 256) {
    b1ps[tid] = b1g[tid]; b2ps[tid] = b2g[tid];
    o2v[tid] = 0.f;                       // correction term at t=0 reads this
    a1v[tid] = 0.f; a1v[256 + tid] = 0.f; // a1_prev at t=0 reads this
  }
  if (tid < 64) b3ps[tid] = b3g[tid];
  if (tid == 0) {
    sca[0] = 1.f; sca[1] = 1.f; sca[2] = 1.f; sca[3] = 1.f;
    sca[4] = 1.f; sca[5] = 1.f; sca[6] = 0.f; sca[7] = 0.f;
  }

  // Initial squared norms (broadcast to all threads).
  float acc1 = 0.f;
  for (int i = tid; i < 65536; i += 512) {
    const float4 v = ((const float4*)W1g)[i];
    acc1 += v.x * v.x + v.y * v.y + v.z * v.z + v.w * v.w;
  }
  const float n1init = block_reduce8(acc1, scr, tid);
  float acc2 = 0.f;
#define N2_ROW(i) { f32x8 t = W2_##i * W2_##i; acc2 += hsum8(t); }
  ROWS16(N2_ROW)
  const float n2init = block_reduce8(acc2, scr, tid);
  float acc3 = 0.f;
#define N3_ROW(i) acc3 += W3x_##i * W3x_##i + W3y_##i * W3y_##i;
  ROWS16(N3_ROW)
  const float n3init = block_reduce8(acc3, scr, tid);

  // Scalar recurrence state: wave 0 owns {s1, n1d}; wave 7 owns {s2,s3,n2,n3}.
  float s1 = 1.f, s2 = 1.f, s3 = 1.f;
  double n1d = (double)n1init;
  float n2 = n2init, n3 = n3init;
  __syncthreads();

  for (int b = 0; b < 16; b++) {
    const int bs = b * 64;
    // ---- prefix: zo[row][j] = Z10[bs+row][j] + sum_{s<bs} cg[s]G[bs+row][s]o1[s][j]
    {
      f32x8 pacc0 = {0.f, 0.f, 0.f, 0.f, 0.f, 0.f, 0.f, 0.f};
      f32x8 pacc1 = pacc0, pacc2 = pacc0, pacc3 = pacc0;
      for (int c0 = 0; c0 < bs; c0 += 32) {
        __syncthreads();
        if (tid < 32) cpre[tid] = cg[c0 + tid];
        {
          const int row = tid >> 3, k4 = (tid & 7) * 4;
          const float4 gv = *(const float4*)(G + (bs + row) * 1024 + c0 + k4);
          Gb[row * 33 + k4 + 0] = gv.x; Gb[row * 33 + k4 + 1] = gv.y;
          Gb[row * 33 + k4 + 2] = gv.z; Gb[row * 33 + k4 + 3] = gv.w;
        }
#pragma unroll
        for (int u = 0; u < 4; u++) {
          const int fi = tid + u * 512;
          ((float4*)scr)[fi] = ((const float4*)(o1g + c0 * 256))[fi];
        }
        __syncthreads();
#pragma unroll 2
        for (int ss = 0; ss < 32; ss++) {
          const float cs = cpre[ss];
          const f32x8 o8 = *(const f32x8*)(scr + ss * 256 + q * 8);
          pacc0 += (Gb[(p * 4 + 0) * 33 + ss] * cs) * o8;
          pacc1 += (Gb[(p * 4 + 1) * 33 + ss] * cs) * o8;
          pacc2 += (Gb[(p * 4 + 2) * 33 + ss] * cs) * o8;
          pacc3 += (Gb[(p * 4 + 3) * 33 + ss] * cs) * o8;
        }
      }
      __syncthreads();
#define ZSTORE(rr)                                                            \
      { const int row = p * 4 + rr;                                           \
        *(f32x8*)(zo + row * 272 + q * 8) =                                   \
            *(const f32x8*)(Z10 + (bs + row) * 256 + q * 8) + pacc##rr; }
      ZSTORE(0) ZSTORE(1) ZSTORE(2) ZSTORE(3)
      // this block's 64x64 Gram square (plain layout) + targets
#pragma unroll
      for (int u = 0; u < 2; u++) {
        const int fi = tid + u * 512;
        const int row = fi >> 4, c4 = fi & 15;
        *(float4*)(Gb + row * 64 + c4 * 4) =
            *(const float4*)(G + (bs + row) * 1024 + bs + c4 * 4);
      }
      ((float4*)Tb)[tid]       = ((const float4*)(Tg + bs * 64))[tid];
      ((float4*)Tb)[tid + 512] = ((const float4*)(Tg + bs * 64))[tid + 512];
      __syncthreads();
    }

    // ---- 64 sequential steps, 8 barrier-fenced phases each
    for (int l = 0; l < 64; l++) {
      const int t = bs + l;
      const int cur = (t & 1) * 256, prv = 256 - cur;
      const float s1c = sca[0], rb1c = sca[1], s2c = sca[2], rb2c = sca[3],
                  s3c = sca[4], rb3c = sca[5], cw2c = sca[6], cw3c = sca[7];

      // W2 lazy-update of prev step's gradient (run by idle waves in B2/C2)
#define W2_UPD()                                                              \
      { const f32x8 o8s = cw2c * (*(const f32x8*)&o2v[q * 8]);                \
        const float* apv = &a1v[prv + p * 16];                                \
        W2_0  += apv[0]  * o8s; W2_1  += apv[1]  * o8s;                       \
        W2_2  += apv[2]  * o8s; W2_3  += apv[3]  * o8s;                       \
        W2_4  += apv[4]  * o8s; W2_5  += apv[5]  * o8s;                       \
        W2_6  += apv[6]  * o8s; W2_7  += apv[7]  * o8s;                       \
        W2_8  += apv[8]  * o8s; W2_9  += apv[9]  * o8s;                       \
        W2_10 += apv[10] * o8s; W2_11 += apv[11] * o8s;                       \
        W2_12 += apv[12] * o8s; W2_13 += apv[13] * o8s;                       \
        W2_14 += apv[14] * o8s; W2_15 += apv[15] * o8s; }

      // ---- Phase A: W3 update + z1 history (4-way) + a1 + dots ----------
      if (t > 0) {
        const float d0s = cw3c * d3v[q * 2], d1s = cw3c * d3v[q * 2 + 1];
#define UPD3_ROW(i)                                                           \
        { const float a2o = a2v[p * 16 + i];                                  \
          W3x_##i += a2o * d0s; W3y_##i += a2o * d1s; }
        ROWS16(UPD3_ROW)
      }
      {
        const int jp = tid >> 2, quarter = tid & 3;   // j-pair {2jp, 2jp+1}
        float ax = 0.f, ay = 0.f;
        for (int lp = quarter; lp < l; lp += 4) {
          const float gcs = ch[lp] * Gb[l * 64 + lp];
          const float2 zr = *(const float2*)&zo[lp * 272 + 2 * jp];
          ax += gcs * zr.x; ay += gcs * zr.y;
        }
        ax = dpp_add<0xB1>(ax); ax = dpp_add<0x4E>(ax);
        ay = dpp_add<0xB1>(ay); ay = dpp_add<0x4E>(ay);
        const float2 zop = *(const float2*)&zo[l * 272 + 2 * jp];
        const float2 b1q = *(const float2*)&b1ps[2 * jp];
        const float2 ap  = *(const float2*)&a1v[prv + 2 * jp];
        const float z1u0 = zop.x + ax, z1u1 = zop.y + ay;
        const float a1x0 = 1.f / (1.f + expf(-(s1c * z1u0 + rb1c * b1q.x)));
        const float a1x1 = 1.f / (1.f + expf(-(s1c * z1u1 + rb1c * b1q.y)));
        if (quarter == 0) {
          *(float2*)&z1v[2 * jp] = make_float2(z1u0, z1u1);
          *(float2*)&a1v[cur + 2 * jp] = make_float2(a1x0, a1x1);
        }
        const float v3 = dpp_allred64(
            quarter == 0 ? a1x0 * a1x0 + a1x1 * a1x1 : 0.f);
        const float vad = dpp_allred64(
            quarter == 0 ? a1x0 * ap.x + a1x1 * ap.y : 0.f);
        if (lane == 0) { dpart[48 + w] = v3; dpart[56 + w] = vad; }
      }
      __syncthreads();

      // ---- Phase B1: z2 partials = a1 @ W2_old --------------------------
      {
        f32x8 acc = {0.f, 0.f, 0.f, 0.f, 0.f, 0.f, 0.f, 0.f};
#define B1_ROW(i) acc += a1v[cur + p * 16 + i] * W2_##i;
        ROWS16(B1_ROW)
        *(f32x8*)&scr[p * 264 + q * 8] = acc;
      }
      __syncthreads();

      // ---- Phase B2: waves 0-3 z2/a2 (+rank-1 correction); 4-7 W2 upd ---
      if (tid < 256) {
        float s = 0.f;
#pragma unroll
        for (int pp = 0; pp < 16; pp++) s += scr[pp * 264 + tid];
        const float adot = ((dpart[56] + dpart[57]) + (dpart[58] + dpart[59]))
                         + ((dpart[60] + dpart[61]) + (dpart[62] + dpart[63]));
        const float z2p = s2c * (s + cw2c * adot * o2v[tid]);
        z2v[tid] = z2p;
        const float a2x = 1.f / (1.f + expf(-(z2p + rb2c * b2ps[tid])));
        a2v[tid] = a2x;
        const float v6 = dpp_allred64(a2x * a2x);
        if ((tid & 63) == 0) dpart[64 + (tid >> 6)] = v6;
      } else if (t > 0) {
        W2_UPD()
      }
      __syncthreads();

      // ---- Phase C1: z3 partials = a2 @ W3 ------------------------------
      {
        float c0a = 0.f, c1a = 0.f;
#define C1_ROW(i)                                                             \
        { const float a2x = a2v[p * 16 + i];                                  \
          c0a += a2x * W3x_##i; c1a += a2x * W3y_##i; }
        ROWS16(C1_ROW)
        scr[(q * 2 + 0) * 17 + p] = c0a;
        scr[(q * 2 + 1) * 17 + p] = c1a;
      }
      __syncthreads();

      // ---- Phase C2: wave 7 softmax/d3/b3; waves 0-3 W2 upd -------------
      if (w == 7) {
        float s = 0.f;
#pragma unroll
        for (int pp = 0; pp < 16; pp++) s += scr[lane * 17 + pp];
        const float z3p = s3c * s;
        const float a3 = 1.f / (1.f + expf(-(z3p + rb3c * b3ps[lane])));
        const float e = expf(-a3);
        const float tot = dpp_allred64(e);
        const float outv = e / tot;
        const float d3 = (Tb[l * 64 + lane] - outv) * a3 * (1.f - a3);
        d3v[lane] = d3;
        const float b3n = rb3c * b3ps[lane] - LRC * d3;
        b3ps[lane] = b3n;
        const float v5 = dpp_allred64(z3p * d3);
        const float v7 = dpp_allred64(d3 * d3);
        const float v10 = dpp_allred64(b3n * b3n);
        if (lane == 0) { dpart[68] = v5; dpart[69] = v7; dpart[70] = v10; }
      } else if (w < 4 && t > 0) {
        W2_UPD()
      }
      __syncthreads();

      // ---- Phase E: o2 partials | fence | intra-wave reduce -------------
      {
        const float d0 = d3v[q * 2 + 0], d1 = d3v[q * 2 + 1];
#define E1_ROW(i) scr[(p * 16 + i) * 33 + q] = W3x_##i * d0 + W3y_##i * d1;
        ROWS16(E1_ROW)
        wave_fence();
        float s = 0.f;
#pragma unroll
        for (int qq = 0; qq < 32; qq++) s += scr[rown * 33 + qq];
        const float a2x = a2v[rown];
        const float o2x = s3c * s * a2x * (1.f - a2x);
        const float b2n = rb2c * b2ps[rown] - LRC * o2x;
        const bool own = (lane & 32) == 0;
        if (own) { o2v[rown] = o2x; b2ps[rown] = b2n; }
        const float v2 = dpp_allred64(own ? z2v[rown] * o2x : 0.f);
        const float v4 = dpp_allred64(own ? o2x * o2x : 0.f);
        const float v9 = dpp_allred64(own ? b2n * b2n : 0.f);
        if (lane == 0) {
          dpart[24 + w] = v2; dpart[32 + w] = v4; dpart[40 + w] = v9;
        }
      }
      __syncthreads();

      // ---- Phase F: o1 partials | fence | intra-wave reduce -------------
      {
        const f32x8 ov8 = *(const f32x8*)&o2v[q * 8];
#define F_ROW(i)                                                              \
        { f32x8 tq = W2_##i * ov8; scr[(p * 16 + i) * 33 + q] = hsum8(tq); }
        ROWS16(F_ROW)
        wave_fence();
        float s = 0.f;
#pragma unroll
        for (int qq = 0; qq < 32; qq++) s += scr[rown * 33 + qq];
        const float a1x = a1v[cur + rown];
        const float o1x = s2c * s * a1x * (1.f - a1x);
        const float b1n = rb1c * b1ps[rown] - LRC * o1x;
        const float z1x = z1v[rown];
        const bool own = (lane & 32) == 0;
        if (own) { zo[l * 272 + rown] = o1x; b1ps[rown] = b1n; }
        const float v0 = dpp_allred64(own ? z1x * o1x : 0.f);
        const float v1 = dpp_allred64(own ? o1x * o1x : 0.f);
        const float v8 = dpp_allred64(own ? b1n * b1n : 0.f);
        if (lane == 0) {
          dpart[0 + w] = v0; dpart[8 + w] = v1; dpart[16 + w] = v8;
        }
      }
      __syncthreads();

      // ---- Phase H: wave 0 f64 n1 chain; wave 7 n2/n3 chains ------------
      if (w == 0) {
        const float dts0 = ((dpart[0] + dpart[1]) + (dpart[2] + dpart[3]))
                         + ((dpart[4] + dpart[5]) + (dpart[6] + dpart[7]));
        const float dts1 = ((dpart[8] + dpart[9]) + (dpart[10] + dpart[11]))
                         + ((dpart[12] + dpart[13]) + (dpart[14] + dpart[15]));
        const float dts8 = ((dpart[16] + dpart[17]) + (dpart[18] + dpart[19]))
                         + ((dpart[20] + dpart[21]) + (dpart[22] + dpart[23]));
        const float c1 = -LRC / s1;
        const double gtt = (double)Gb[l * 65];
        n1d = n1d + 2.0 * (double)c1 * (double)dts0 +
              (double)c1 * (double)c1 * gtt * (double)dts1;
        const double w1n = (double)s1 * sqrt(n1d);
        s1 = (float)((double)s1 / fmax(w1n, (double)EPSV));
        if (lane == 0) {
          ch[l] = c1;
          sca[0] = s1;
          sca[1] = 1.f / fmaxf(sqrtf(dts8), EPSV);
        }
      } else if (w == 7) {
        const float dts2 = ((dpart[24] + dpart[25]) + (dpart[26] + dpart[27]))
                         + ((dpart[28] + dpart[29]) + (dpart[30] + dpart[31]));
        const float dts4 = ((dpart[32] + dpart[33]) + (dpart[34] + dpart[35]))
                         + ((dpart[36] + dpart[37]) + (dpart[38] + dpart[39]));
        const float dts9 = ((dpart[40] + dpart[41]) + (dpart[42] + dpart[43]))
                         + ((dpart[44] + dpart[45]) + (dpart[46] + dpart[47]));
        const float dts3 = ((dpart[48] + dpart[49]) + (dpart[50] + dpart[51]))
                         + ((dpart[52] + dpart[53]) + (dpart[54] + dpart[55]));
        const float dts6 = (dpart[64] + dpart[65]) + (dpart[66] + dpart[67]);
        const float dts5 = dpart[68], dts7 = dpart[69], dts10 = dpart[70];
        const float n2p = n2 - 2.f * LRC * dts2 + LRC * LRC * dts3 * dts4;
        const float r2s = 1.f / fmaxf(sqrtf(n2p), EPSV);
        n2 = n2p * r2s * r2s;
        const float cw2n = -LRC / s2;
        s2 = s2 * r2s;
        const float n3p = n3 - 2.f * LRC * dts5 + LRC * LRC * dts6 * dts7;
        const float r3s = 1.f / fmaxf(sqrtf(n3p), EPSV);
        n3 = n3p * r3s * r3s;
        const float cw3n = -LRC / s3;
        s3 = s3 * r3s;
        if (lane == 0) {
          sca[2] = s2;
          sca[3] = 1.f / fmaxf(sqrtf(dts9), EPSV);
          sca[4] = s3;
          sca[5] = 1.f / fmaxf(sqrtf(dts10), EPSV);
          sca[6] = cw2n;
          sca[7] = cw3n;
        }
      }
      __syncthreads();
    }

    // ---- per-block flush of o1 (from zo) and c (from ch) to global
    {
#pragma unroll
      for (int u = 0; u < 4; u++) {
        const int chunk = tid + u * 512;          // 0..2047
        const int row = chunk >> 5, c8 = chunk & 31;
        *(f32x8*)(o1g + (bs + row) * 256 + c8 * 8) =
            *(const f32x8*)(zo + row * 272 + c8 * 8);
      }
      if (tid < 64) cg[bs + tid] = ch[tid];
    }
    // next block's prefix __syncthreads() drains these stores before reads
  }

  // ---- epilogue: apply deferred update of step 1023, write scaled outputs
  {
    const float cw2f = sca[6], cw3f = sca[7];
    const float s2f = sca[2], s3f = sca[4];
    const f32x8 o8s = cw2f * (*(const f32x8*)&o2v[q * 8]);
    const float d0s = cw3f * d3v[q * 2], d1s = cw3f * d3v[q * 2 + 1];
#define FIN_ROW(i)                                                            \
    { const float a1o = a1v[256 + p * 16 + i]; /* parity of t=1023 */         \
      W2_##i += a1o * o8s;                                                    \
      const float a2o = a2v[p * 16 + i];                                      \
      W3x_##i += a2o * d0s; W3y_##i += a2o * d1s;                             \
      const int row = p * 16 + i;                                             \
      *(f32x8*)(outW2 + row * 256 + q * 8) = s2f * W2_##i;                    \
      outW3[row * 64 + q * 2]     = s3f * W3x_##i;                            \
      outW3[row * 64 + q * 2 + 1] = s3f * W3y_##i; }
    ROWS16(FIN_ROW)
    if (tid == 0) sclg[0] = sca[0];
  }
}

// ---------------------------------------------------------------- launch ----
extern "C" void kernel_launch(void* const* d_in, const int* in_sizes, int n_in,
                              void* d_out, int out_size, void* d_ws,
                              size_t ws_size, hipStream_t stream) {
  (void)in_sizes; (void)n_in; (void)out_size; (void)ws_size;
  const float* X   = (const float*)d_in[0];
  const float* Tg  = (const float*)d_in[1];
  const float* W1g = (const float*)d_in[2];
  const float* b1g = (const float*)d_in[3];
  const float* W2g = (const float*)d_in[4];
  const float* b2g = (const float*)d_in[5];
  const float* W3g = (const float*)d_in[6];
  const float* b3g = (const float*)d_in[7];
  float* out = (float*)d_out;
  float* ws  = (float*)d_ws;

  float* G    = ws;
  float* Z10  = G + 1048576;
  float* o1g  = Z10 + 262144;
  float* cg   = o1g + 262144;
  float* sclg = cg + 1024;

  (void)hipFuncSetAttribute((const void*)k2_seq,
                            hipFuncAttributeMaxDynamicSharedMemorySize,
                            SMEM_BYTES);

  k_gram<<<dim3(16, 16), 256, 0, stream>>>(X, G);
  k_z10<<<dim3(4, 16), 256, 0, stream>>>(X, W1g, Z10);
  k2_seq<<<dim3(1), dim3(512), SMEM_BYTES, stream>>>(
      Tg, W1g, b1g, W2g, b2g, W3g, b3g, G, Z10, o1g, cg, sclg,
      out + 262144, out + 327680);
  k_w1out<<<dim3(4, 16), 256, 0, stream>>>(X, o1g, cg, W1g, sclg, out);
}

// Round 6
// 8474.851 us; speedup vs baseline: 1.2457x; 1.0215x over previous
//
#include <hip/hip_runtime.h>
#include <math.h>

// Backprop_29188597744223 — 1024-step sequential MLP training scan.
//
//   k_gram : G = X·Xᵀ (lower triangle + diag tiles), grid-parallel
//   k_z10  : Z10 = X·W1_init, grid-parallel
//   k2_seq : ONE workgroup, 512 threads (8 waves). 6 barrier-fenced phases,
//            with two intra-phase cross-wave handoffs via LDS spin-flags:
//              A : wave0 runs the f64 n1 chain, wave7 the n2/n3 chains for
//                  step t-1 (publish sca + flags) WHILE other waves run the
//                  z1 history loop (lp<l-1); all spin, add the lp=l-1 term
//                  via sca[8]=c1, W3 deferred update, a1, dots.
//              B1: z2 partials = a1 @ W2_old -> scr
//              B2: waves 0-3: z2 reduce + rank-1 correction, a2, |a2|² dot;
//                  waves 4-7: W2 deferred update (reads prev-parity o2v)
//              C1: z3 partials = a2 @ W3 -> csc (separate buffer!)
//              CE: wave7: softmax/d3/b3 + dots, fence, flagD; waves 0-3:
//                  W2 update then spin; waves 4-6 spin; then ALL: o2
//                  partials | fence | intra-wave reduce -> o2v (parity),
//                  b2, dots  (C2+E merged, one barrier saved)
//              F : o1 partials | fence | intra-wave reduce -> zo, b1, dots
//            Per-block tail: chains for step bs+63 (waves 0/7) before flush.
//            W2: thread (p,q) owns rows 16p..+15 × cols 8q..+7 (16 f32x8).
//            W3: same thread owns rows 16p..+15 × cols 2q..+1 (32 scalars).
//            Lazy scales s2/s3; biases pre-norm with rb folded at use; no
//            global stores in the step loop (o1/c flushed per 64-step block).
//   k_w1out: W1_final = s1_f·(W1_init + Xᵀ·diag(c)·O1), grid-parallel

#define LRC  0.01f
#define EPSV 1e-8f

typedef float f32x8 __attribute__((ext_vector_type(8)));

#define SMEM_FLOATS 37768
#define SMEM_BYTES  (SMEM_FLOATS * 4)

#define ROWS16(OP)                                                            \
  OP(0) OP(1) OP(2) OP(3) OP(4) OP(5) OP(6) OP(7)                             \
  OP(8) OP(9) OP(10) OP(11) OP(12) OP(13) OP(14) OP(15)

__device__ __forceinline__ float hsum8(f32x8 v) {
  return ((v.s0 + v.s1) + (v.s2 + v.s3)) + ((v.s4 + v.s5) + (v.s6 + v.s7));
}

// ---- DPP reductions (VALU-rate; no DS pipe) --------------------------------
template <int CTRL>
__device__ __forceinline__ float dpp_add(float v) {
  const int s = __builtin_amdgcn_update_dpp(0, __builtin_bit_cast(int, v),
                                            CTRL, 0xf, 0xf, true);
  return v + __builtin_bit_cast(float, s);
}

// Full 64-lane sum, result broadcast to all lanes via readlane(63).
__device__ __forceinline__ float dpp_allred64(float v) {
  v = dpp_add<0x111>(v);   // row_shr:1
  v = dpp_add<0x112>(v);   // row_shr:2
  v = dpp_add<0x114>(v);   // row_shr:4
  v = dpp_add<0x118>(v);   // row_shr:8  -> lane15/31/47/63 hold row sums
  v = dpp_add<0x142>(v);   // row_bcast:15
  v = dpp_add<0x143>(v);   // row_bcast:31 -> lane 63 holds total
  return __builtin_bit_cast(float,
      __builtin_amdgcn_readlane(__builtin_bit_cast(int, v), 63));
}

__device__ __forceinline__ float wave_allred(float v) {  // init-path only
#pragma unroll
  for (int off = 32; off > 0; off >>= 1) v += __shfl_xor(v, off);
  return v;
}

// In-wave fence: order own-wave LDS writes -> LDS reads without s_barrier.
__device__ __forceinline__ void wave_fence() {
  __builtin_amdgcn_sched_barrier(0);
  asm volatile("s_waitcnt lgkmcnt(0)" ::: "memory");
  __builtin_amdgcn_sched_barrier(0);
}

// Spin on an LDS flag until it equals `want` (producer fenced before write).
__device__ __forceinline__ void lds_spin(volatile int* f, int want) {
  while (*f != want) {}
}

#define FMA16(c, a, b)                                                        \
  c[0][0] += a.x * b.x; c[0][1] += a.x * b.y; c[0][2] += a.x * b.z; c[0][3] += a.x * b.w; \
  c[1][0] += a.y * b.x; c[1][1] += a.y * b.y; c[1][2] += a.y * b.z; c[1][3] += a.y * b.w; \
  c[2][0] += a.z * b.x; c[2][1] += a.z * b.y; c[2][2] += a.z * b.z; c[2][3] += a.z * b.w; \
  c[3][0] += a.w * b.x; c[3][1] += a.w * b.y; c[3][2] += a.w * b.z; c[3][3] += a.w * b.w;

// ---------------------------------------------------------------- k_gram ----
__global__ __launch_bounds__(256) void k_gram(const float* __restrict__ X,
                                              float* __restrict__ G) {
  const int bi = blockIdx.y, bj = blockIdx.x;
  if (bj > bi) return;
  __shared__ float Xa[32][68];
  __shared__ float Xb[32][68];
  const int tid = threadIdx.x;
  const int tx = tid & 15, ty = tid >> 4;
  float c[4][4] = {};
  for (int k0 = 0; k0 < 1024; k0 += 32) {
    __syncthreads();
    {
      const int row = tid >> 2, kk = (tid & 3) * 8;
      const float* pa = X + (bi * 64 + row) * 1024 + k0 + kk;
      const float4 a0 = *(const float4*)pa;
      const float4 a1 = *(const float4*)(pa + 4);
      Xa[kk + 0][row] = a0.x; Xa[kk + 1][row] = a0.y;
      Xa[kk + 2][row] = a0.z; Xa[kk + 3][row] = a0.w;
      Xa[kk + 4][row] = a1.x; Xa[kk + 5][row] = a1.y;
      Xa[kk + 6][row] = a1.z; Xa[kk + 7][row] = a1.w;
      const float* pb = X + (bj * 64 + row) * 1024 + k0 + kk;
      const float4 b0 = *(const float4*)pb;
      const float4 b1 = *(const float4*)(pb + 4);
      Xb[kk + 0][row] = b0.x; Xb[kk + 1][row] = b0.y;
      Xb[kk + 2][row] = b0.z; Xb[kk + 3][row] = b0.w;
      Xb[kk + 4][row] = b1.x; Xb[kk + 5][row] = b1.y;
      Xb[kk + 6][row] = b1.z; Xb[kk + 7][row] = b1.w;
    }
    __syncthreads();
#pragma unroll
    for (int kk = 0; kk < 32; kk++) {
      const float4 a = *(const float4*)&Xa[kk][ty * 4];
      const float4 b = *(const float4*)&Xb[kk][tx * 4];
      FMA16(c, a, b)
    }
  }
#pragma unroll
  for (int ii = 0; ii < 4; ii++) {
    *(float4*)(G + (bi * 64 + ty * 4 + ii) * 1024 + bj * 64 + tx * 4) =
        make_float4(c[ii][0], c[ii][1], c[ii][2], c[ii][3]);
  }
}

// ----------------------------------------------------------------- k_z10 ----
__global__ __launch_bounds__(256) void k_z10(const float* __restrict__ X,
                                             const float* __restrict__ W1g,
                                             float* __restrict__ Z10) {
  const int bi = blockIdx.y, bj = blockIdx.x;
  __shared__ float At[32][68];
  __shared__ float Bt[32][68];
  const int tid = threadIdx.x;
  const int tx = tid & 15, ty = tid >> 4;
  float c[4][4] = {};
  for (int k0 = 0; k0 < 1024; k0 += 32) {
    __syncthreads();
    {
      const int row = tid >> 2, kk = (tid & 3) * 8;
      const float* pa = X + (bi * 64 + row) * 1024 + k0 + kk;
      const float4 a0 = *(const float4*)pa;
      const float4 a1 = *(const float4*)(pa + 4);
      At[kk + 0][row] = a0.x; At[kk + 1][row] = a0.y;
      At[kk + 2][row] = a0.z; At[kk + 3][row] = a0.w;
      At[kk + 4][row] = a1.x; At[kk + 5][row] = a1.y;
      At[kk + 6][row] = a1.z; At[kk + 7][row] = a1.w;
      const int kr = tid >> 3, j8 = (tid & 7) * 8;
      const float* pb = W1g + (k0 + kr) * 256 + bj * 64 + j8;
      *(float4*)&Bt[kr][j8]     = *(const float4*)pb;
      *(float4*)&Bt[kr][j8 + 4] = *(const float4*)(pb + 4);
    }
    __syncthreads();
#pragma unroll
    for (int kk = 0; kk < 32; kk++) {
      const float4 a = *(const float4*)&At[kk][ty * 4];
      const float4 b = *(const float4*)&Bt[kk][tx * 4];
      FMA16(c, a, b)
    }
  }
#pragma unroll
  for (int ii = 0; ii < 4; ii++) {
    *(float4*)(Z10 + (bi * 64 + ty * 4 + ii) * 256 + bj * 64 + tx * 4) =
        make_float4(c[ii][0], c[ii][1], c[ii][2], c[ii][3]);
  }
}

// --------------------------------------------------------------- k_w1out ----
__global__ __launch_bounds__(256) void k_w1out(
    const float* __restrict__ X, const float* __restrict__ o1g,
    const float* __restrict__ cg, const float* __restrict__ W1g,
    const float* __restrict__ sclg, float* __restrict__ outW1) {
  const int bi = blockIdx.y, bj = blockIdx.x;
  __shared__ float At[32][68];
  __shared__ float Bt[32][68];
  const int tid = threadIdx.x;
  const int tx = tid & 15, ty = tid >> 4;
  float c[4][4] = {};
  for (int k0 = 0; k0 < 1024; k0 += 32) {
    __syncthreads();
    {
      const int kr = tid >> 3, m8 = (tid & 7) * 8;
      const float* pa = X + (k0 + kr) * 1024 + bi * 64 + m8;
      *(float4*)&At[kr][m8]     = *(const float4*)pa;
      *(float4*)&At[kr][m8 + 4] = *(const float4*)(pa + 4);
      const float cs = cg[k0 + kr];
      const float* pb = o1g + (k0 + kr) * 256 + bj * 64 + m8;
      float4 b0 = *(const float4*)pb;
      float4 b1 = *(const float4*)(pb + 4);
      b0.x *= cs; b0.y *= cs; b0.z *= cs; b0.w *= cs;
      b1.x *= cs; b1.y *= cs; b1.z *= cs; b1.w *= cs;
      *(float4*)&Bt[kr][m8]     = b0;
      *(float4*)&Bt[kr][m8 + 4] = b1;
    }
    __syncthreads();
#pragma unroll
    for (int kk = 0; kk < 32; kk++) {
      const float4 a = *(const float4*)&At[kk][ty * 4];
      const float4 b = *(const float4*)&Bt[kk][tx * 4];
      FMA16(c, a, b)
    }
  }
  const float s1f = sclg[0];
#pragma unroll
  for (int ii = 0; ii < 4; ii++) {
    const int row = bi * 64 + ty * 4 + ii;
    const float4 w = *(const float4*)(W1g + row * 256 + bj * 64 + tx * 4);
    *(float4*)(outW1 + row * 256 + bj * 64 + tx * 4) =
        make_float4(s1f * (w.x + c[ii][0]), s1f * (w.y + c[ii][1]),
                    s1f * (w.z + c[ii][2]), s1f * (w.w + c[ii][3]));
  }
}

// ---------------------------------------------------------------- k2_seq ----
__device__ __forceinline__ float block_reduce8(float v, float* tmp, int tid) {
  v = wave_allred(v);
  __syncthreads();
  if ((tid & 63) == 0) tmp[tid >> 6] = v;
  __syncthreads();
  float s = 0.f;
#pragma unroll
  for (int w = 0; w < 8; w++) s += tmp[w];
  __syncthreads();
  return s;
}

#define SUM8(x0, x1) (((x0.x + x0.y) + (x0.z + x0.w)) +                       \
                      ((x1.x + x1.y) + (x1.z + x1.w)))

__global__ __launch_bounds__(512, 1) void k2_seq(
    const float* __restrict__ Tg, const float* __restrict__ W1g,
    const float* __restrict__ b1g, const float* __restrict__ W2g,
    const float* __restrict__ b2g, const float* __restrict__ W3g,
    const float* __restrict__ b3g, const float* __restrict__ G,
    const float* __restrict__ Z10, float* __restrict__ o1g,
    float* __restrict__ cg, float* __restrict__ sclg,
    float* __restrict__ outW2, float* __restrict__ outW3) {
  extern __shared__ float sm[];
  float* const zo   = sm;            // [64][272]: z1p row l until step l, then o1
  float* const Gb   = sm + 17408;    // [64][64] plain / [64][33] prefix staging
  float* const scr  = sm + 21504;    // 8448: prefix staging / B1 partials / E,F partials
  float* const Tb   = sm + 29952;    // [64][64] targets for this block
  float* const a1v  = sm + 34048;    // [2][256] double-buffered by step parity
  float* const z1v  = sm + 34560;    // 256 (z1u, for dts0)
  float* const z2v  = sm + 34816;    // 256 (physical z2)
  float* const a2v  = sm + 35072;    // 256
  float* const o2v  = sm + 35328;    // [2][256] parity-buffered (CE writes cur)
  float* const b1ps = sm + 35840;    // 256 (pre-norm physical b1)
  float* const b2ps = sm + 36096;    // 256
  float* const d3v  = sm + 36352;    // 64
  float* const b3ps = sm + 36416;    // 64
  float* const ch   = sm + 36480;    // 64  in-block c coefficients
  float* const dpart= sm + 36544;    // 88  dot wave-partials (see map below)
  float* const sca  = sm + 36632;    // 12  {s1,rb1,s2,rb2,s3,rb3,cw2,cw3,c1,..}
  float* const cpre = sm + 36644;    // 32
  float* const csc  = sm + 36676;    // 1088: C1 z3-partials [64][17]
  int*   const flgi = (int*)(sm + 37764);  // 3 spin-flags {f0, f7, fD}

  // dpart map: [0..7] v0(F) [8..15] v1(F) [16..23] v8(F)
  //            [24..31] v2(CE) [32..39] v4(CE) [40..47] v9(CE)
  //            [48..55] v3 par0 (A), [56..63] v3 par1 (A)
  //            [64..71] vad (A)  [80..83] v6 (B2)  [84..86] v5,v7,v10 (CE w7)

  const int tid = threadIdx.x;
  const int lane = tid & 63;
  const int w = tid >> 6;            // wave 0..7
  const int p = tid >> 5;            // 0..15 : 16-row group
  const int q = tid & 31;            // 0..31 : 8-col group (W2) / 2-col (W3)
  const int rown = 32 * w + (lane & 31);  // intra-wave reduce row (CE/F)

  // ---- persistent per-thread state as named SSA values (no arrays!) ----
  // W2_phys = s2 * R2 ; W3_phys = s3 * R3  (lazy scales)
  f32x8 W2_0, W2_1, W2_2, W2_3, W2_4, W2_5, W2_6, W2_7,
        W2_8, W2_9, W2_10, W2_11, W2_12, W2_13, W2_14, W2_15;
  float W3x_0, W3x_1, W3x_2, W3x_3, W3x_4, W3x_5, W3x_6, W3x_7,
        W3x_8, W3x_9, W3x_10, W3x_11, W3x_12, W3x_13, W3x_14, W3x_15;
  float W3y_0, W3y_1, W3y_2, W3y_3, W3y_4, W3y_5, W3y_6, W3y_7,
        W3y_8, W3y_9, W3y_10, W3y_11, W3y_12, W3y_13, W3y_14, W3y_15;

#define INIT_ROW(i)                                                           \
  { const int row = p * 16 + i;                                               \
    W2_##i  = *(const f32x8*)(W2g + row * 256 + q * 8);                       \
    W3x_##i = W3g[row * 64 + q * 2];                                          \
    W3y_##i = W3g[row * 64 + q * 2 + 1]; }
  ROWS16(INIT_ROW)

  if (tid < 256) {
    b1ps[tid] = b1g[tid]; b2ps[tid] = b2g[tid];
    o2v[tid] = 0.f; o2v[256 + tid] = 0.f;   // t=0 correction reads zeros
    a1v[tid] = 0.f; a1v[256 + tid] = 0.f;   // a1_prev at t=0 reads zeros
  }
  if (tid < 64) b3ps[tid] = b3g[tid];
  if (tid == 0) {
    sca[0] = 1.f; sca[1] = 1.f; sca[2] = 1.f; sca[3] = 1.f;
    sca[4] = 1.f; sca[5] = 1.f; sca[6] = 0.f; sca[7] = 0.f; sca[8] = 0.f;
    flgi[0] = -1; flgi[1] = -1; flgi[2] = -1;
  }

  // Initial squared norms (broadcast to all threads).
  float acc1 = 0.f;
  for (int i = tid; i < 65536; i += 512) {
    const float4 v = ((const float4*)W1g)[i];
    acc1 += v.x * v.x + v.y * v.y + v.z * v.z + v.w * v.w;
  }
  const float n1init = block_reduce8(acc1, scr, tid);
  float acc2 = 0.f;
#define N2_ROW(i) { f32x8 t = W2_##i * W2_##i; acc2 += hsum8(t); }
  ROWS16(N2_ROW)
  const float n2init = block_reduce8(acc2, scr, tid);
  float acc3 = 0.f;
#define N3_ROW(i) acc3 += W3x_##i * W3x_##i + W3y_##i * W3y_##i;
  ROWS16(N3_ROW)
  const float n3init = block_reduce8(acc3, scr, tid);

  // Scalar recurrence state: wave 0 owns {s1, n1d}; wave 7 owns {s2,s3,n2,n3}.
  float s1 = 1.f, s2 = 1.f, s3 = 1.f;
  double n1d = (double)n1init;
  float n2 = n2init, n3 = n3init;
  __syncthreads();

  // chain0: f64 n1 recurrence + s1/rb1/c1 for in-block step lidx (wave 0).
  auto chain0 = [&](const int lidx) {
    const float4 qa0 = *(const float4*)&dpart[0];
    const float4 qa1 = *(const float4*)&dpart[4];
    const float4 qb0 = *(const float4*)&dpart[8];
    const float4 qb1 = *(const float4*)&dpart[12];
    const float4 qc0 = *(const float4*)&dpart[16];
    const float4 qc1 = *(const float4*)&dpart[20];
    const float dts0 = SUM8(qa0, qa1);
    const float dts1 = SUM8(qb0, qb1);
    const float dts8 = SUM8(qc0, qc1);
    const float c1 = -LRC / s1;
    const double gtt = (double)Gb[lidx * 65];
    n1d = n1d + 2.0 * (double)c1 * (double)dts0 +
          (double)c1 * (double)c1 * gtt * (double)dts1;
    const double w1n = (double)s1 * sqrt(n1d);
    s1 = (float)((double)s1 / fmax(w1n, (double)EPSV));
    if (lane == 0) {
      ch[lidx] = c1;
      sca[0] = s1;
      sca[1] = 1.f / fmaxf(sqrtf(dts8), EPSV);
      sca[8] = c1;
    }
  };
  // chain7: n2/n3 recurrences for the step whose parity is `par` (wave 7).
  auto chain7 = [&](const int par) {
    const float4 qd0 = *(const float4*)&dpart[24];
    const float4 qd1 = *(const float4*)&dpart[28];
    const float4 qe0 = *(const float4*)&dpart[32];
    const float4 qe1 = *(const float4*)&dpart[36];
    const float4 qf0 = *(const float4*)&dpart[40];
    const float4 qf1 = *(const float4*)&dpart[44];
    const float4 qg0 = *(const float4*)&dpart[48 + par * 8];
    const float4 qg1 = *(const float4*)&dpart[52 + par * 8];
    const float4 qh  = *(const float4*)&dpart[80];
    const float dts2 = SUM8(qd0, qd1);
    const float dts4 = SUM8(qe0, qe1);
    const float dts9 = SUM8(qf0, qf1);
    const float dts3 = SUM8(qg0, qg1);
    const float dts6 = (qh.x + qh.y) + (qh.z + qh.w);
    const float dts5 = dpart[84], dts7 = dpart[85], dts10 = dpart[86];
    const float n2p = n2 - 2.f * LRC * dts2 + LRC * LRC * dts3 * dts4;
    const float r2s = 1.f / fmaxf(sqrtf(n2p), EPSV);
    n2 = n2p * r2s * r2s;
    const float cw2n = -LRC / s2;
    s2 = s2 * r2s;
    const float n3p = n3 - 2.f * LRC * dts5 + LRC * LRC * dts6 * dts7;
    const float r3s = 1.f / fmaxf(sqrtf(n3p), EPSV);
    n3 = n3p * r3s * r3s;
    const float cw3n = -LRC / s3;
    s3 = s3 * r3s;
    if (lane == 0) {
      sca[2] = s2;
      sca[3] = 1.f / fmaxf(sqrtf(dts9), EPSV);
      sca[4] = s3;
      sca[5] = 1.f / fmaxf(sqrtf(dts10), EPSV);
      sca[6] = cw2n;
      sca[7] = cw3n;
    }
  };

  for (int b = 0; b < 16; b++) {
    const int bs = b * 64;
    // ---- prefix: zo[row][j] = Z10[bs+row][j] + sum_{s<bs} cg[s]G[bs+row][s]o1[s][j]
    {
      f32x8 pacc0 = {0.f, 0.f, 0.f, 0.f, 0.f, 0.f, 0.f, 0.f};
      f32x8 pacc1 = pacc0, pacc2 = pacc0, pacc3 = pacc0;
      for (int c0 = 0; c0 < bs; c0 += 32) {
        __syncthreads();
        if (tid < 32) cpre[tid] = cg[c0 + tid];
        {
          const int row = tid >> 3, k4 = (tid & 7) * 4;
          const float4 gv = *(const float4*)(G + (bs + row) * 1024 + c0 + k4);
          Gb[row * 33 + k4 + 0] = gv.x; Gb[row * 33 + k4 + 1] = gv.y;
          Gb[row * 33 + k4 + 2] = gv.z; Gb[row * 33 + k4 + 3] = gv.w;
        }
#pragma unroll
        for (int u = 0; u < 4; u++) {
          const int fi = tid + u * 512;
          ((float4*)scr)[fi] = ((const float4*)(o1g + c0 * 256))[fi];
        }
        __syncthreads();
#pragma unroll 2
        for (int ss = 0; ss < 32; ss++) {
          const float cs = cpre[ss];
          const f32x8 o8 = *(const f32x8*)(scr + ss * 256 + q * 8);
          pacc0 += (Gb[(p * 4 + 0) * 33 + ss] * cs) * o8;
          pacc1 += (Gb[(p * 4 + 1) * 33 + ss] * cs) * o8;
          pacc2 += (Gb[(p * 4 + 2) * 33 + ss] * cs) * o8;
          pacc3 += (Gb[(p * 4 + 3) * 33 + ss] * cs) * o8;
        }
      }
      __syncthreads();
#define ZSTORE(rr)                                                            \
      { const int row = p * 4 + rr;                                           \
        *(f32x8*)(zo + row * 272 + q * 8) =                                   \
            *(const f32x8*)(Z10 + (bs + row) * 256 + q * 8) + pacc##rr; }
      ZSTORE(0) ZSTORE(1) ZSTORE(2) ZSTORE(3)
      // this block's 64x64 Gram square (plain layout) + targets
#pragma unroll
      for (int u = 0; u < 2; u++) {
        const int fi = tid + u * 512;
        const int row = fi >> 4, c4 = fi & 15;
        *(float4*)(Gb + row * 64 + c4 * 4) =
            *(const float4*)(G + (bs + row) * 1024 + bs + c4 * 4);
      }
      ((float4*)Tb)[tid]       = ((const float4*)(Tg + bs * 64))[tid];
      ((float4*)Tb)[tid + 512] = ((const float4*)(Tg + bs * 64))[tid + 512];
      __syncthreads();
    }

    // ---- 64 sequential steps, 6 barrier-fenced phases each
    for (int l = 0; l < 64; l++) {
      const int t = bs + l;
      const int cur = (t & 1) * 256, prv = 256 - cur;

      // W2 lazy-update of prev step's gradient (idle waves in B2/CE)
#define W2_UPD()                                                              \
      { const float cw2u = sca[6];                                            \
        const f32x8 o8s = cw2u * (*(const f32x8*)&o2v[prv + q * 8]);          \
        const float* apv = &a1v[prv + p * 16];                                \
        W2_0  += apv[0]  * o8s; W2_1  += apv[1]  * o8s;                       \
        W2_2  += apv[2]  * o8s; W2_3  += apv[3]  * o8s;                       \
        W2_4  += apv[4]  * o8s; W2_5  += apv[5]  * o8s;                       \
        W2_6  += apv[6]  * o8s; W2_7  += apv[7]  * o8s;                       \
        W2_8  += apv[8]  * o8s; W2_9  += apv[9]  * o8s;                       \
        W2_10 += apv[10] * o8s; W2_11 += apv[11] * o8s;                       \
        W2_12 += apv[12] * o8s; W2_13 += apv[13] * o8s;                       \
        W2_14 += apv[14] * o8s; W2_15 += apv[15] * o8s; }

      // ======== Phase A: chains (waves 0/7, flags) || history; a1 ========
      if (l > 0) {
        if (w == 0) {
          chain0(l - 1);
          wave_fence();
          if (lane == 0) *(volatile int*)&flgi[0] = t;
        } else if (w == 7) {
          chain7((t - 1) & 1);
          wave_fence();
          if (lane == 0) *(volatile int*)&flgi[1] = t;
        }
      }
      {
        const int jp = tid >> 2, quarter = tid & 3;   // j-pair {2jp, 2jp+1}
        float ax = 0.f, ay = 0.f;
        for (int lp = quarter; lp < l - 1; lp += 4) {
          const float gcs = ch[lp] * Gb[l * 64 + lp];
          const float2 zr = *(const float2*)&zo[lp * 272 + 2 * jp];
          ax += gcs * zr.x; ay += gcs * zr.y;
        }
        if (l > 0) {
          if (w != 0) lds_spin(&flgi[0], t);
          if (w != 7) lds_spin(&flgi[1], t);
        }
        asm volatile("" ::: "memory");
        const float s1c = sca[0], rb1c = sca[1];
        if (l > 0 && ((l - 1) & 3) == quarter) {   // newest term via sca[8]=c1
          const float gcs = sca[8] * Gb[l * 64 + (l - 1)];
          const float2 zr = *(const float2*)&zo[(l - 1) * 272 + 2 * jp];
          ax += gcs * zr.x; ay += gcs * zr.y;
        }
        ax = dpp_add<0xB1>(ax); ax = dpp_add<0x4E>(ax);
        ay = dpp_add<0xB1>(ay); ay = dpp_add<0x4E>(ay);
        const float2 zop = *(const float2*)&zo[l * 272 + 2 * jp];
        const float2 b1q = *(const float2*)&b1ps[2 * jp];
        const float2 ap  = *(const float2*)&a1v[prv + 2 * jp];
        const float z1u0 = zop.x + ax, z1u1 = zop.y + ay;
        const float a1x0 = 1.f / (1.f + expf(-(s1c * z1u0 + rb1c * b1q.x)));
        const float a1x1 = 1.f / (1.f + expf(-(s1c * z1u1 + rb1c * b1q.y)));
        if (quarter == 0) {
          *(float2*)&z1v[2 * jp] = make_float2(z1u0, z1u1);
          *(float2*)&a1v[cur + 2 * jp] = make_float2(a1x0, a1x1);
        }
        const float v3 = dpp_allred64(
            quarter == 0 ? a1x0 * a1x0 + a1x1 * a1x1 : 0.f);
        const float vad = dpp_allred64(
            quarter == 0 ? a1x0 * ap.x + a1x1 * ap.y : 0.f);
        if (lane == 0) {
          dpart[48 + (t & 1) * 8 + w] = v3;
          dpart[64 + w] = vad;
        }
      }
      // W3 deferred update (prev step; needs sca[7] post-spin)
      if (t > 0) {
        const float cw3c = sca[7];
        const float d0s = cw3c * d3v[q * 2], d1s = cw3c * d3v[q * 2 + 1];
#define UPD3_ROW(i)                                                           \
        { const float a2o = a2v[p * 16 + i];                                  \
          W3x_##i += a2o * d0s; W3y_##i += a2o * d1s; }
        ROWS16(UPD3_ROW)
      }
      __syncthreads();

      // ======== Phase B1: z2 partials = a1 @ W2_old ======================
      {
        f32x8 acc = {0.f, 0.f, 0.f, 0.f, 0.f, 0.f, 0.f, 0.f};
#define B1_ROW(i) acc += a1v[cur + p * 16 + i] * W2_##i;
        ROWS16(B1_ROW)
        *(f32x8*)&scr[p * 264 + q * 8] = acc;
      }
      __syncthreads();

      // ======== Phase B2: waves 0-3 z2/a2 (+correction); 4-7 W2 upd ======
      if (tid < 256) {
        const float s2c = sca[2], rb2c = sca[3], cw2c = sca[6];
        float s = 0.f;
#pragma unroll
        for (int pp = 0; pp < 16; pp++) s += scr[pp * 264 + tid];
        const float adot = ((dpart[64] + dpart[65]) + (dpart[66] + dpart[67]))
                         + ((dpart[68] + dpart[69]) + (dpart[70] + dpart[71]));
        const float z2p = s2c * (s + cw2c * adot * o2v[prv + tid]);
        z2v[tid] = z2p;
        const float a2x = 1.f / (1.f + expf(-(z2p + rb2c * b2ps[tid])));
        a2v[tid] = a2x;
        const float v6 = dpp_allred64(a2x * a2x);
        if ((tid & 63) == 0) dpart[80 + (tid >> 6)] = v6;
      } else if (t > 0) {
        W2_UPD()
      }
      __syncthreads();

      // ======== Phase C1: z3 partials = a2 @ W3 -> csc ===================
      {
        float c0a = 0.f, c1a = 0.f;
#define C1_ROW(i)                                                             \
        { const float a2x = a2v[p * 16 + i];                                  \
          c0a += a2x * W3x_##i; c1a += a2x * W3y_##i; }
        ROWS16(C1_ROW)
        csc[(q * 2 + 0) * 17 + p] = c0a;
        csc[(q * 2 + 1) * 17 + p] = c1a;
      }
      __syncthreads();

      // ======== Phase CE: softmax (wave7, flagD) || W2 upd; then o2 ======
      {
        if (w == 7) {
          const float s3c = sca[4], rb3c = sca[5];
          float s = 0.f;
#pragma unroll
          for (int pp = 0; pp < 16; pp++) s += csc[lane * 17 + pp];
          const float z3p = s3c * s;
          const float a3 = 1.f / (1.f + expf(-(z3p + rb3c * b3ps[lane])));
          const float e = expf(-a3);
          const float tot = dpp_allred64(e);
          const float outv = e / tot;
          const float d3 = (Tb[l * 64 + lane] - outv) * a3 * (1.f - a3);
          d3v[lane] = d3;
          const float b3n = rb3c * b3ps[lane] - LRC * d3;
          b3ps[lane] = b3n;
          const float v5 = dpp_allred64(z3p * d3);
          const float v7 = dpp_allred64(d3 * d3);
          const float v10 = dpp_allred64(b3n * b3n);
          if (lane == 0) { dpart[84] = v5; dpart[85] = v7; dpart[86] = v10; }
          wave_fence();
          if (lane == 0) *(volatile int*)&flgi[2] = t;
        } else if (w < 4) {
          if (t > 0) { W2_UPD() }
          lds_spin((volatile int*)&flgi[2], t);
        } else {
          lds_spin((volatile int*)&flgi[2], t);
        }
        asm volatile("" ::: "memory");
        // E-part (all waves): o2 partials | fence | intra-wave reduce
        const float s3c = sca[4], rb2c = sca[3];
        const float d0 = d3v[q * 2 + 0], d1 = d3v[q * 2 + 1];
#define E1_ROW(i) scr[(p * 16 + i) * 33 + q] = W3x_##i * d0 + W3y_##i * d1;
        ROWS16(E1_ROW)
        wave_fence();
        float s = 0.f;
#pragma unroll
        for (int qq = 0; qq < 32; qq++) s += scr[rown * 33 + qq];
        const float a2x = a2v[rown];
        const float o2x = s3c * s * a2x * (1.f - a2x);
        const float b2n = rb2c * b2ps[rown] - LRC * o2x;
        const bool own = (lane & 32) == 0;
        if (own) { o2v[cur + rown] = o2x; b2ps[rown] = b2n; }
        const float v2 = dpp_allred64(own ? z2v[rown] * o2x : 0.f);
        const float v4 = dpp_allred64(own ? o2x * o2x : 0.f);
        const float v9 = dpp_allred64(own ? b2n * b2n : 0.f);
        if (lane == 0) {
          dpart[24 + w] = v2; dpart[32 + w] = v4; dpart[40 + w] = v9;
        }
      }
      __syncthreads();

      // ======== Phase F: o1 partials | fence | intra-wave reduce =========
      {
        const float s2c = sca[2], rb1c = sca[1];
        const f32x8 ov8 = *(const f32x8*)&o2v[cur + q * 8];
#define F_ROW(i)                                                              \
        { f32x8 tq = W2_##i * ov8; scr[(p * 16 + i) * 33 + q] = hsum8(tq); }
        ROWS16(F_ROW)
        wave_fence();
        float s = 0.f;
#pragma unroll
        for (int qq = 0; qq < 32; qq++) s += scr[rown * 33 + qq];
        const float a1x = a1v[cur + rown];
        const float o1x = s2c * s * a1x * (1.f - a1x);
        const float b1n = rb1c * b1ps[rown] - LRC * o1x;
        const float z1x = z1v[rown];
        const bool own = (lane & 32) == 0;
        if (own) { zo[l * 272 + rown] = o1x; b1ps[rown] = b1n; }
        const float v0 = dpp_allred64(own ? z1x * o1x : 0.f);
        const float v1 = dpp_allred64(own ? o1x * o1x : 0.f);
        const float v8 = dpp_allred64(own ? b1n * b1n : 0.f);
        if (lane == 0) {
          dpart[0 + w] = v0; dpart[8 + w] = v1; dpart[16 + w] = v8;
        }
      }
      __syncthreads();
    }

    // ---- tail: chains for step bs+63 (produce ch[63] + next-block sca)
    if (w == 0) chain0(63);
    else if (w == 7) chain7((bs + 63) & 1);
    __syncthreads();

    // ---- per-block flush of o1 (from zo) and c (from ch) to global
    {
#pragma unroll
      for (int u = 0; u < 4; u++) {
        const int chunk = tid + u * 512;          // 0..2047
        const int row = chunk >> 5, c8 = chunk & 31;
        *(f32x8*)(o1g + (bs + row) * 256 + c8 * 8) =
            *(const f32x8*)(zo + row * 272 + c8 * 8);
      }
      if (tid < 64) cg[bs + tid] = ch[tid];
    }
    // next block's prefix __syncthreads() drains these stores before reads
  }

  // ---- epilogue: apply deferred update of step 1023, write scaled outputs
  {
    const float cw2f = sca[6], cw3f = sca[7];
    const float s2f = sca[2], s3f = sca[4];
    // t=1023 parity: cur = 256 for both a1v and o2v
    const f32x8 o8s = cw2f * (*(const f32x8*)&o2v[256 + q * 8]);
    const float d0s = cw3f * d3v[q * 2], d1s = cw3f * d3v[q * 2 + 1];
#define FIN_ROW(i)                                                            \
    { const float a1o = a1v[256 + p * 16 + i];                                \
      W2_##i += a1o * o8s;                                                    \
      const float a2o = a2v[p * 16 + i];                                      \
      W3x_##i += a2o * d0s; W3y_##i += a2o * d1s;                             \
      const int row = p * 16 + i;                                             \
      *(f32x8*)(outW2 + row * 256 + q * 8) = s2f * W2_##i;                    \
      outW3[row * 64 + q * 2]     = s3f * W3x_##i;                            \
      outW3[row * 64 + q * 2 + 1] = s3f * W3y_##i; }
    ROWS16(FIN_ROW)
    if (tid == 0) sclg[0] = sca[0];
  }
}

// ---------------------------------------------------------------- launch ----
extern "C" void kernel_launch(void* const* d_in, const int* in_sizes, int n_in,
                              void* d_out, int out_size, void* d_ws,
                              size_t ws_size, hipStream_t stream) {
  (void)in_sizes; (void)n_in; (void)out_size; (void)ws_size;
  const float* X   = (const float*)d_in[0];
  const float* Tg  = (const float*)d_in[1];
  const float* W1g = (const float*)d_in[2];
  const float* b1g = (const float*)d_in[3];
  const float* W2g = (const float*)d_in[4];
  const float* b2g = (const float*)d_in[5];
  const float* W3g = (const float*)d_in[6];
  const float* b3g = (const float*)d_in[7];
  float* out = (float*)d_out;
  float* ws  = (float*)d_ws;

  float* G    = ws;
  float* Z10  = G + 1048576;
  float* o1g  = Z10 + 262144;
  float* cg   = o1g + 262144;
  float* sclg = cg + 1024;

  (void)hipFuncSetAttribute((const void*)k2_seq,
                            hipFuncAttributeMaxDynamicSharedMemorySize,
                            SMEM_BYTES);

  k_gram<<<dim3(16, 16), 256, 0, stream>>>(X, G);
  k_z10<<<dim3(4, 16), 256, 0, stream>>>(X, W1g, Z10);
  k2_seq<<<dim3(1), dim3(512), SMEM_BYTES, stream>>>(
      Tg, W1g, b1g, W2g, b2g, W3g, b3g, G, Z10, o1g, cg, sclg,
      out + 262144, out + 327680);
  k_w1out<<<dim3(4, 16), 256, 0, stream>>>(X, o1g, cg, W1g, sclg, out);
}

// Round 9
// 8278.690 us; speedup vs baseline: 1.2752x; 1.0237x over previous
//
#include <hip/hip_runtime.h>
#include <math.h>

// Backprop_29188597744223 — 1024-step sequential MLP training scan.
//
//   k_gram : G = X·Xᵀ (lower triangle + diag tiles), grid-parallel
//   k_z10  : Z10 = X·W1_init, grid-parallel
//   k2_seq : ONE workgroup, 512 threads (8 waves). 6 barrier-fenced phases,
//            two intra-phase cross-wave spin-flag handoffs:
//              A : wave0 f64 n1 chain / wave7 n2-n3 chains for step t-1
//                  (setprio(1), publish sca + flags) WHILE other waves run
//                  the FULL z1 history loop (c1 for the newest term was
//                  published one step early into ch[l-1]) and the DPP tree;
//                  spin AFTER the tree (chain latency hidden); sigmoid; dots.
//              B1: z2 partials = a1 @ W2_old -> scr
//              B2: waves 0-3: z2 reduce + rank-1 correction, a2, |a2|² dot;
//                  waves 4-7: W2 deferred update (reads prev-parity o2v)
//              C1: z3 partials = a2 @ W3 -> csc (separate buffer)
//              CE: wave7: softmax/d3/b3 + dots (setprio), fence, flagD;
//                  waves 0-3: W2 update then spin; waves 4-6 spin; then ALL:
//                  o2 partials | fence | intra-wave reduce -> o2v (parity)
//              F : o1 partials | fence | intra-wave reduce -> zo, b1, dots
//            Early-c1: chain0(lidx) consumes step-lidx dots and publishes
//            c1(lidx+1) = -LR/s1_post(lidx) into ch[lidx+1] + sca[8]; block
//            boundary copies sca[8] -> ch[0] after the cg flush.
//            W2: thread (p,q) owns rows 16p..+15 × cols 8q..+7 (16 f32x8).
//            W3: same thread owns rows 16p..+15 × cols 2q..+1 (32 scalars).
//            Lazy scales s2/s3; biases pre-norm with rb folded at use; no
//            global stores in the step loop (o1/c flushed per 64-step block).
//   k_w1out: W1_final = s1_f·(W1_init + Xᵀ·diag(c)·O1), grid-parallel

#define LRC  0.01f
#define EPSV 1e-8f

typedef float f32x8 __attribute__((ext_vector_type(8)));

#define SMEM_FLOATS 37768
#define SMEM_BYTES  (SMEM_FLOATS * 4)

#define ROWS16(OP)                                                            \
  OP(0) OP(1) OP(2) OP(3) OP(4) OP(5) OP(6) OP(7)                             \
  OP(8) OP(9) OP(10) OP(11) OP(12) OP(13) OP(14) OP(15)

__device__ __forceinline__ float hsum8(f32x8 v) {
  return ((v.s0 + v.s1) + (v.s2 + v.s3)) + ((v.s4 + v.s5) + (v.s6 + v.s7));
}

// ---- DPP reductions (VALU-rate; no DS pipe) --------------------------------
template <int CTRL>
__device__ __forceinline__ float dpp_add(float v) {
  const int s = __builtin_amdgcn_update_dpp(0, __builtin_bit_cast(int, v),
                                            CTRL, 0xf, 0xf, true);
  return v + __builtin_bit_cast(float, s);
}

// Full 64-lane sum, result broadcast to all lanes via readlane(63).
__device__ __forceinline__ float dpp_allred64(float v) {
  v = dpp_add<0x111>(v);   // row_shr:1
  v = dpp_add<0x112>(v);   // row_shr:2
  v = dpp_add<0x114>(v);   // row_shr:4
  v = dpp_add<0x118>(v);   // row_shr:8  -> lane15/31/47/63 hold row sums
  v = dpp_add<0x142>(v);   // row_bcast:15
  v = dpp_add<0x143>(v);   // row_bcast:31 -> lane 63 holds total
  return __builtin_bit_cast(float,
      __builtin_amdgcn_readlane(__builtin_bit_cast(int, v), 63));
}

__device__ __forceinline__ float wave_allred(float v) {  // init-path only
#pragma unroll
  for (int off = 32; off > 0; off >>= 1) v += __shfl_xor(v, off);
  return v;
}

// In-wave fence: order own-wave LDS writes -> LDS reads without s_barrier.
__device__ __forceinline__ void wave_fence() {
  __builtin_amdgcn_sched_barrier(0);
  asm volatile("s_waitcnt lgkmcnt(0)" ::: "memory");
  __builtin_amdgcn_sched_barrier(0);
}

// Spin on an LDS flag until it equals `want` (producer fenced before write).
__device__ __forceinline__ void lds_spin(volatile int* f, int want) {
  while (*f != want) {}
}

#define FMA16(c, a, b)                                                        \
  c[0][0] += a.x * b.x; c[0][1] += a.x * b.y; c[0][2] += a.x * b.z; c[0][3] += a.x * b.w; \
  c[1][0] += a.y * b.x; c[1][1] += a.y * b.y; c[1][2] += a.y * b.z; c[1][3] += a.y * b.w; \
  c[2][0] += a.z * b.x; c[2][1] += a.z * b.y; c[2][2] += a.z * b.z; c[2][3] += a.z * b.w; \
  c[3][0] += a.w * b.x; c[3][1] += a.w * b.y; c[3][2] += a.w * b.z; c[3][3] += a.w * b.w;

// ---------------------------------------------------------------- k_gram ----
__global__ __launch_bounds__(256) void k_gram(const float* __restrict__ X,
                                              float* __restrict__ G) {
  const int bi = blockIdx.y, bj = blockIdx.x;
  if (bj > bi) return;
  __shared__ float Xa[32][68];
  __shared__ float Xb[32][68];
  const int tid = threadIdx.x;
  const int tx = tid & 15, ty = tid >> 4;
  float c[4][4] = {};
  for (int k0 = 0; k0 < 1024; k0 += 32) {
    __syncthreads();
    {
      const int row = tid >> 2, kk = (tid & 3) * 8;
      const float* pa = X + (bi * 64 + row) * 1024 + k0 + kk;
      const float4 a0 = *(const float4*)pa;
      const float4 a1 = *(const float4*)(pa + 4);
      Xa[kk + 0][row] = a0.x; Xa[kk + 1][row] = a0.y;
      Xa[kk + 2][row] = a0.z; Xa[kk + 3][row] = a0.w;
      Xa[kk + 4][row] = a1.x; Xa[kk + 5][row] = a1.y;
      Xa[kk + 6][row] = a1.z; Xa[kk + 7][row] = a1.w;
      const float* pb = X + (bj * 64 + row) * 1024 + k0 + kk;
      const float4 b0 = *(const float4*)pb;
      const float4 b1 = *(const float4*)(pb + 4);
      Xb[kk + 0][row] = b0.x; Xb[kk + 1][row] = b0.y;
      Xb[kk + 2][row] = b0.z; Xb[kk + 3][row] = b0.w;
      Xb[kk + 4][row] = b1.x; Xb[kk + 5][row] = b1.y;
      Xb[kk + 6][row] = b1.z; Xb[kk + 7][row] = b1.w;
    }
    __syncthreads();
#pragma unroll
    for (int kk = 0; kk < 32; kk++) {
      const float4 a = *(const float4*)&Xa[kk][ty * 4];
      const float4 b = *(const float4*)&Xb[kk][tx * 4];
      FMA16(c, a, b)
    }
  }
#pragma unroll
  for (int ii = 0; ii < 4; ii++) {
    *(float4*)(G + (bi * 64 + ty * 4 + ii) * 1024 + bj * 64 + tx * 4) =
        make_float4(c[ii][0], c[ii][1], c[ii][2], c[ii][3]);
  }
}

// ----------------------------------------------------------------- k_z10 ----
__global__ __launch_bounds__(256) void k_z10(const float* __restrict__ X,
                                             const float* __restrict__ W1g,
                                             float* __restrict__ Z10) {
  const int bi = blockIdx.y, bj = blockIdx.x;
  __shared__ float At[32][68];
  __shared__ float Bt[32][68];
  const int tid = threadIdx.x;
  const int tx = tid & 15, ty = tid >> 4;
  float c[4][4] = {};
  for (int k0 = 0; k0 < 1024; k0 += 32) {
    __syncthreads();
    {
      const int row = tid >> 2, kk = (tid & 3) * 8;
      const float* pa = X + (bi * 64 + row) * 1024 + k0 + kk;
      const float4 a0 = *(const float4*)pa;
      const float4 a1 = *(const float4*)(pa + 4);
      At[kk + 0][row] = a0.x; At[kk + 1][row] = a0.y;
      At[kk + 2][row] = a0.z; At[kk + 3][row] = a0.w;
      At[kk + 4][row] = a1.x; At[kk + 5][row] = a1.y;
      At[kk + 6][row] = a1.z; At[kk + 7][row] = a1.w;
      const int kr = tid >> 3, j8 = (tid & 7) * 8;
      const float* pb = W1g + (k0 + kr) * 256 + bj * 64 + j8;
      *(float4*)&Bt[kr][j8]     = *(const float4*)pb;
      *(float4*)&Bt[kr][j8 + 4] = *(const float4*)(pb + 4);
    }
    __syncthreads();
#pragma unroll
    for (int kk = 0; kk < 32; kk++) {
      const float4 a = *(const float4*)&At[kk][ty * 4];
      const float4 b = *(const float4*)&Bt[kk][tx * 4];
      FMA16(c, a, b)
    }
  }
#pragma unroll
  for (int ii = 0; ii < 4; ii++) {
    *(float4*)(Z10 + (bi * 64 + ty * 4 + ii) * 256 + bj * 64 + tx * 4) =
        make_float4(c[ii][0], c[ii][1], c[ii][2], c[ii][3]);
  }
}

// --------------------------------------------------------------- k_w1out ----
__global__ __launch_bounds__(256) void k_w1out(
    const float* __restrict__ X, const float* __restrict__ o1g,
    const float* __restrict__ cg, const float* __restrict__ W1g,
    const float* __restrict__ sclg, float* __restrict__ outW1) {
  const int bi = blockIdx.y, bj = blockIdx.x;
  __shared__ float At[32][68];
  __shared__ float Bt[32][68];
  const int tid = threadIdx.x;
  const int tx = tid & 15, ty = tid >> 4;
  float c[4][4] = {};
  for (int k0 = 0; k0 < 1024; k0 += 32) {
    __syncthreads();
    {
      const int kr = tid >> 3, m8 = (tid & 7) * 8;
      const float* pa = X + (k0 + kr) * 1024 + bi * 64 + m8;
      *(float4*)&At[kr][m8]     = *(const float4*)pa;
      *(float4*)&At[kr][m8 + 4] = *(const float4*)(pa + 4);
      const float cs = cg[k0 + kr];
      const float* pb = o1g + (k0 + kr) * 256 + bj * 64 + m8;
      float4 b0 = *(const float4*)pb;
      float4 b1 = *(const float4*)(pb + 4);
      b0.x *= cs; b0.y *= cs; b0.z *= cs; b0.w *= cs;
      b1.x *= cs; b1.y *= cs; b1.z *= cs; b1.w *= cs;
      *(float4*)&Bt[kr][m8]     = b0;
      *(float4*)&Bt[kr][m8 + 4] = b1;
    }
    __syncthreads();
#pragma unroll
    for (int kk = 0; kk < 32; kk++) {
      const float4 a = *(const float4*)&At[kk][ty * 4];
      const float4 b = *(const float4*)&Bt[kk][tx * 4];
      FMA16(c, a, b)
    }
  }
  const float s1f = sclg[0];
#pragma unroll
  for (int ii = 0; ii < 4; ii++) {
    const int row = bi * 64 + ty * 4 + ii;
    const float4 w = *(const float4*)(W1g + row * 256 + bj * 64 + tx * 4);
    *(float4*)(outW1 + row * 256 + bj * 64 + tx * 4) =
        make_float4(s1f * (w.x + c[ii][0]), s1f * (w.y + c[ii][1]),
                    s1f * (w.z + c[ii][2]), s1f * (w.w + c[ii][3]));
  }
}

// ---------------------------------------------------------------- k2_seq ----
__device__ __forceinline__ float block_reduce8(float v, float* tmp, int tid) {
  v = wave_allred(v);
  __syncthreads();
  if ((tid & 63) == 0) tmp[tid >> 6] = v;
  __syncthreads();
  float s = 0.f;
#pragma unroll
  for (int w = 0; w < 8; w++) s += tmp[w];
  __syncthreads();
  return s;
}

#define SUM8(x0, x1) (((x0.x + x0.y) + (x0.z + x0.w)) +                       \
                      ((x1.x + x1.y) + (x1.z + x1.w)))

__global__ __launch_bounds__(512, 1) void k2_seq(
    const float* __restrict__ Tg, const float* __restrict__ W1g,
    const float* __restrict__ b1g, const float* __restrict__ W2g,
    const float* __restrict__ b2g, const float* __restrict__ W3g,
    const float* __restrict__ b3g, const float* __restrict__ G,
    const float* __restrict__ Z10, float* __restrict__ o1g,
    float* __restrict__ cg, float* __restrict__ sclg,
    float* __restrict__ outW2, float* __restrict__ outW3) {
  extern __shared__ float sm[];
  float* const zo   = sm;            // [64][272]: z1p row l until step l, then o1
  float* const Gb   = sm + 17408;    // [64][64] plain / [64][33] prefix staging
  float* const scr  = sm + 21504;    // 8448: prefix staging / B1 partials / E,F partials
  float* const Tb   = sm + 29952;    // [64][64] targets for this block
  float* const a1v  = sm + 34048;    // [2][256] double-buffered by step parity
  float* const z1v  = sm + 34560;    // 256 (z1u, for dts0)
  float* const z2v  = sm + 34816;    // 256 (physical z2)
  float* const a2v  = sm + 35072;    // 256
  float* const o2v  = sm + 35328;    // [2][256] parity-buffered (CE writes cur)
  float* const b1ps = sm + 35840;    // 256 (pre-norm physical b1)
  float* const b2ps = sm + 36096;    // 256
  float* const d3v  = sm + 36352;    // 64
  float* const b3ps = sm + 36416;    // 64
  float* const ch   = sm + 36480;    // 64  in-block c coefficients (early-published)
  float* const dpart= sm + 36544;    // 88  dot wave-partials (see map below)
  float* const sca  = sm + 36632;    // 12  {s1,rb1,s2,rb2,s3,rb3,cw2,cw3,c1,..}
  float* const cpre = sm + 36644;    // 32
  float* const csc  = sm + 36676;    // 1088: C1 z3-partials [64][17]
  int*   const flgi = (int*)(sm + 37764);  // 3 spin-flags {f0, f7, fD}

  // dpart map: [0..7] v0(F) [8..15] v1(F) [16..23] v8(F)
  //            [24..31] v2(CE) [32..39] v4(CE) [40..47] v9(CE)
  //            [48..55] v3 par0 (A), [56..63] v3 par1 (A)
  //            [64..71] vad (A)  [80..83] v6 (B2)  [84..86] v5,v7,v10 (CE w7)

  const int tid = threadIdx.x;
  const int lane = tid & 63;
  const int w = tid >> 6;            // wave 0..7
  const int p = tid >> 5;            // 0..15 : 16-row group
  const int q = tid & 31;            // 0..31 : 8-col group (W2) / 2-col (W3)
  const int rown = 32 * w + (lane & 31);  // intra-wave reduce row (CE/F)

  // ---- persistent per-thread state as named SSA values (no arrays!) ----
  // W2_phys = s2 * R2 ; W3_phys = s3 * R3  (lazy scales)
  f32x8 W2_0, W2_1, W2_2, W2_3, W2_4, W2_5, W2_6, W2_7,
        W2_8, W2_9, W2_10, W2_11, W2_12, W2_13, W2_14, W2_15;
  float W3x_0, W3x_1, W3x_2, W3x_3, W3x_4, W3x_5, W3x_6, W3x_7,
        W3x_8, W3x_9, W3x_10, W3x_11, W3x_12, W3x_13, W3x_14, W3x_15;
  float W3y_0, W3y_1, W3y_2, W3y_3, W3y_4, W3y_5, W3y_6, W3y_7,
        W3y_8, W3y_9, W3y_10, W3y_11, W3y_12, W3y_13, W3y_14, W3y_15;

#define INIT_ROW(i)                                                           \
  { const int row = p * 16 + i;                                               \
    W2_##i  = *(const f32x8*)(W2g + row * 256 + q * 8);                       \
    W3x_##i = W3g[row * 64 + q * 2];                                          \
    W3y_##i = W3g[row * 64 + q * 2 + 1]; }
  ROWS16(INIT_ROW)

  if (tid < 256) {
    b1ps[tid] = b1g[tid]; b2ps[tid] = b2g[tid];
    o2v[tid] = 0.f; o2v[256 + tid] = 0.f;   // t=0 correction reads zeros
    a1v[tid] = 0.f; a1v[256 + tid] = 0.f;   // a1_prev at t=0 reads zeros
  }
  if (tid < 64) b3ps[tid] = b3g[tid];
  if (tid == 0) {
    sca[0] = 1.f; sca[1] = 1.f; sca[2] = 1.f; sca[3] = 1.f;
    sca[4] = 1.f; sca[5] = 1.f; sca[6] = 0.f; sca[7] = 0.f;
    sca[8] = -LRC;          // c1(0) = -LR/s1_init
    ch[0] = -LRC;           // early-published c1 for step 0
    flgi[0] = -1; flgi[1] = -1; flgi[2] = -1;
  }

  // Initial squared norms (broadcast to all threads).
  float acc1 = 0.f;
  for (int i = tid; i < 65536; i += 512) {
    const float4 v = ((const float4*)W1g)[i];
    acc1 += v.x * v.x + v.y * v.y + v.z * v.z + v.w * v.w;
  }
  const float n1init = block_reduce8(acc1, scr, tid);
  float acc2 = 0.f;
#define N2_ROW(i) { f32x8 t = W2_##i * W2_##i; acc2 += hsum8(t); }
  ROWS16(N2_ROW)
  const float n2init = block_reduce8(acc2, scr, tid);
  float acc3 = 0.f;
#define N3_ROW(i) acc3 += W3x_##i * W3x_##i + W3y_##i * W3y_##i;
  ROWS16(N3_ROW)
  const float n3init = block_reduce8(acc3, scr, tid);

  // Scalar recurrence state: wave 0 owns {s1, n1d, c1cur}; wave 7 owns
  // {s2, s3, n2, n3}.
  float s1 = 1.f, s2 = 1.f, s3 = 1.f;
  float c1cur = -LRC;        // c1 for the step about to be consumed
  double n1d = (double)n1init;
  float n2 = n2init, n3 = n3init;
  __syncthreads();

  // chain0 (wave 0): consume step-lidx dots; update n1d/s1; publish
  // c1(lidx+1) into ch[lidx+1] (if in-range) + sca[8], and s1/rb1.
  auto chain0 = [&](const int lidx) {
    const float4 qa0 = *(const float4*)&dpart[0];
    const float4 qa1 = *(const float4*)&dpart[4];
    const float4 qb0 = *(const float4*)&dpart[8];
    const float4 qb1 = *(const float4*)&dpart[12];
    const float4 qc0 = *(const float4*)&dpart[16];
    const float4 qc1 = *(const float4*)&dpart[20];
    const float dts0 = SUM8(qa0, qa1);
    const float dts1 = SUM8(qb0, qb1);
    const float dts8 = SUM8(qc0, qc1);
    const double c1d = (double)c1cur;     // c1(lidx), published a step ago
    const double gtt = (double)Gb[lidx * 65];
    n1d = n1d + 2.0 * c1d * (double)dts0 +
          c1d * c1d * gtt * (double)dts1;
    const double w1n = (double)s1 * sqrt(n1d);
    s1 = (float)((double)s1 / fmax(w1n, (double)EPSV));
    c1cur = -LRC / s1;                    // c1(lidx+1)
    if (lane == 0) {
      if (lidx < 63) ch[lidx + 1] = c1cur;
      sca[0] = s1;
      sca[1] = 1.f / fmaxf(sqrtf(dts8), EPSV);
      sca[8] = c1cur;
    }
  };
  // chain7 (wave 7): n2/n3 recurrences for the step whose parity is `par`.
  auto chain7 = [&](const int par) {
    const float4 qd0 = *(const float4*)&dpart[24];
    const float4 qd1 = *(const float4*)&dpart[28];
    const float4 qe0 = *(const float4*)&dpart[32];
    const float4 qe1 = *(const float4*)&dpart[36];
    const float4 qf0 = *(const float4*)&dpart[40];
    const float4 qf1 = *(const float4*)&dpart[44];
    const float4 qg0 = *(const float4*)&dpart[48 + par * 8];
    const float4 qg1 = *(const float4*)&dpart[52 + par * 8];
    const float4 qh  = *(const float4*)&dpart[80];
    const float dts2 = SUM8(qd0, qd1);
    const float dts4 = SUM8(qe0, qe1);
    const float dts9 = SUM8(qf0, qf1);
    const float dts3 = SUM8(qg0, qg1);
    const float dts6 = (qh.x + qh.y) + (qh.z + qh.w);
    const float dts5 = dpart[84], dts7 = dpart[85], dts10 = dpart[86];
    const float n2p = n2 - 2.f * LRC * dts2 + LRC * LRC * dts3 * dts4;
    const float r2s = 1.f / fmaxf(sqrtf(n2p), EPSV);
    n2 = n2p * r2s * r2s;
    const float cw2n = -LRC / s2;
    s2 = s2 * r2s;
    const float n3p = n3 - 2.f * LRC * dts5 + LRC * LRC * dts6 * dts7;
    const float r3s = 1.f / fmaxf(sqrtf(n3p), EPSV);
    n3 = n3p * r3s * r3s;
    const float cw3n = -LRC / s3;
    s3 = s3 * r3s;
    if (lane == 0) {
      sca[2] = s2;
      sca[3] = 1.f / fmaxf(sqrtf(dts9), EPSV);
      sca[4] = s3;
      sca[5] = 1.f / fmaxf(sqrtf(dts10), EPSV);
      sca[6] = cw2n;
      sca[7] = cw3n;
    }
  };

  for (int b = 0; b < 16; b++) {
    const int bs = b * 64;
    // ---- prefix: zo[row][j] = Z10[bs+row][j] + sum_{s<bs} cg[s]G[bs+row][s]o1[s][j]
    {
      f32x8 pacc0 = {0.f, 0.f, 0.f, 0.f, 0.f, 0.f, 0.f, 0.f};
      f32x8 pacc1 = pacc0, pacc2 = pacc0, pacc3 = pacc0;
      for (int c0 = 0; c0 < bs; c0 += 32) {
        __syncthreads();
        if (tid < 32) cpre[tid] = cg[c0 + tid];
        {
          const int row = tid >> 3, k4 = (tid & 7) * 4;
          const float4 gv = *(const float4*)(G + (bs + row) * 1024 + c0 + k4);
          Gb[row * 33 + k4 + 0] = gv.x; Gb[row * 33 + k4 + 1] = gv.y;
          Gb[row * 33 + k4 + 2] = gv.z; Gb[row * 33 + k4 + 3] = gv.w;
        }
#pragma unroll
        for (int u = 0; u < 4; u++) {
          const int fi = tid + u * 512;
          ((float4*)scr)[fi] = ((const float4*)(o1g + c0 * 256))[fi];
        }
        __syncthreads();
#pragma unroll 2
        for (int ss = 0; ss < 32; ss++) {
          const float cs = cpre[ss];
          const f32x8 o8 = *(const f32x8*)(scr + ss * 256 + q * 8);
          pacc0 += (Gb[(p * 4 + 0) * 33 + ss] * cs) * o8;
          pacc1 += (Gb[(p * 4 + 1) * 33 + ss] * cs) * o8;
          pacc2 += (Gb[(p * 4 + 2) * 33 + ss] * cs) * o8;
          pacc3 += (Gb[(p * 4 + 3) * 33 + ss] * cs) * o8;
        }
      }
      __syncthreads();
#define ZSTORE(rr)                                                            \
      { const int row = p * 4 + rr;                                           \
        *(f32x8*)(zo + row * 272 + q * 8) =                                   \
            *(const f32x8*)(Z10 + (bs + row) * 256 + q * 8) + pacc##rr; }
      ZSTORE(0) ZSTORE(1) ZSTORE(2) ZSTORE(3)
      // this block's 64x64 Gram square (plain layout) + targets
#pragma unroll
      for (int u = 0; u < 2; u++) {
        const int fi = tid + u * 512;
        const int row = fi >> 4, c4 = fi & 15;
        *(float4*)(Gb + row * 64 + c4 * 4) =
            *(const float4*)(G + (bs + row) * 1024 + bs + c4 * 4);
      }
      ((float4*)Tb)[tid]       = ((const float4*)(Tg + bs * 64))[tid];
      ((float4*)Tb)[tid + 512] = ((const float4*)(Tg + bs * 64))[tid + 512];
      __syncthreads();
    }

    // ---- 64 sequential steps, 6 barrier-fenced phases each
    for (int l = 0; l < 64; l++) {
      const int t = bs + l;
      const int cur = (t & 1) * 256, prv = 256 - cur;

      // W2 lazy-update of prev step's gradient (idle waves in B2/CE)
#define W2_UPD()                                                              \
      { const float cw2u = sca[6];                                            \
        const f32x8 o8s = cw2u * (*(const f32x8*)&o2v[prv + q * 8]);          \
        const float* apv = &a1v[prv + p * 16];                                \
        W2_0  += apv[0]  * o8s; W2_1  += apv[1]  * o8s;                       \
        W2_2  += apv[2]  * o8s; W2_3  += apv[3]  * o8s;                       \
        W2_4  += apv[4]  * o8s; W2_5  += apv[5]  * o8s;                       \
        W2_6  += apv[6]  * o8s; W2_7  += apv[7]  * o8s;                       \
        W2_8  += apv[8]  * o8s; W2_9  += apv[9]  * o8s;                       \
        W2_10 += apv[10] * o8s; W2_11 += apv[11] * o8s;                       \
        W2_12 += apv[12] * o8s; W2_13 += apv[13] * o8s;                       \
        W2_14 += apv[14] * o8s; W2_15 += apv[15] * o8s; }

      // ======== Phase A: chains (waves 0/7, flags) || full history ========
      if (l > 0) {
        if (w == 0) {
          __builtin_amdgcn_s_setprio(1);
          chain0(l - 1);
          __builtin_amdgcn_s_setprio(0);
          wave_fence();
          if (lane == 0) *(volatile int*)&flgi[0] = t;
        } else if (w == 7) {
          __builtin_amdgcn_s_setprio(1);
          chain7((t - 1) & 1);
          __builtin_amdgcn_s_setprio(0);
          wave_fence();
          if (lane == 0) *(volatile int*)&flgi[1] = t;
        }
      }
      {
        const int jp = tid >> 2, quarter = tid & 3;   // j-pair {2jp, 2jp+1}
        float ax = 0.f, ay = 0.f;
        // FULL history loop: ch[l-1] was early-published last step.
        for (int lp = quarter; lp < l; lp += 4) {
          const float gcs = ch[lp] * Gb[l * 64 + lp];
          const float2 zr = *(const float2*)&zo[lp * 272 + 2 * jp];
          ax += gcs * zr.x; ay += gcs * zr.y;
        }
        ax = dpp_add<0xB1>(ax); ax = dpp_add<0x4E>(ax);
        ay = dpp_add<0xB1>(ay); ay = dpp_add<0x4E>(ay);
        // Spin AFTER the tree: chain latency hidden under history+tree.
        if (l > 0) {
          if (w != 0) lds_spin((volatile int*)&flgi[0], t);
          if (w != 7) lds_spin((volatile int*)&flgi[1], t);
        }
        asm volatile("" ::: "memory");
        const float s1c = sca[0], rb1c = sca[1];
        const float2 zop = *(const float2*)&zo[l * 272 + 2 * jp];
        const float2 b1q = *(const float2*)&b1ps[2 * jp];
        const float2 ap  = *(const float2*)&a1v[prv + 2 * jp];
        const float z1u0 = zop.x + ax, z1u1 = zop.y + ay;
        const float a1x0 = 1.f / (1.f + expf(-(s1c * z1u0 + rb1c * b1q.x)));
        const float a1x1 = 1.f / (1.f + expf(-(s1c * z1u1 + rb1c * b1q.y)));
        if (quarter == 0) {
          *(float2*)&z1v[2 * jp] = make_float2(z1u0, z1u1);
          *(float2*)&a1v[cur + 2 * jp] = make_float2(a1x0, a1x1);
        }
        const float v3 = dpp_allred64(
            quarter == 0 ? a1x0 * a1x0 + a1x1 * a1x1 : 0.f);
        const float vad = dpp_allred64(
            quarter == 0 ? a1x0 * ap.x + a1x1 * ap.y : 0.f);
        if (lane == 0) {
          dpart[48 + (t & 1) * 8 + w] = v3;
          dpart[64 + w] = vad;
        }
      }
      // W3 deferred update (prev step; needs sca[7] post-spin)
      if (t > 0) {
        const float cw3c = sca[7];
        const float d0s = cw3c * d3v[q * 2], d1s = cw3c * d3v[q * 2 + 1];
#define UPD3_ROW(i)                                                           \
        { const float a2o = a2v[p * 16 + i];                                  \
          W3x_##i += a2o * d0s; W3y_##i += a2o * d1s; }
        ROWS16(UPD3_ROW)
      }
      __syncthreads();

      // ======== Phase B1: z2 partials = a1 @ W2_old ======================
      {
        f32x8 acc = {0.f, 0.f, 0.f, 0.f, 0.f, 0.f, 0.f, 0.f};
#define B1_ROW(i) acc += a1v[cur + p * 16 + i] * W2_##i;
        ROWS16(B1_ROW)
        *(f32x8*)&scr[p * 264 + q * 8] = acc;
      }
      __syncthreads();

      // ======== Phase B2: waves 0-3 z2/a2 (+correction); 4-7 W2 upd ======
      if (tid < 256) {
        const float s2c = sca[2], rb2c = sca[3], cw2c = sca[6];
        float s = 0.f;
#pragma unroll
        for (int pp = 0; pp < 16; pp++) s += scr[pp * 264 + tid];
        const float adot = ((dpart[64] + dpart[65]) + (dpart[66] + dpart[67]))
                         + ((dpart[68] + dpart[69]) + (dpart[70] + dpart[71]));
        const float z2p = s2c * (s + cw2c * adot * o2v[prv + tid]);
        z2v[tid] = z2p;
        const float a2x = 1.f / (1.f + expf(-(z2p + rb2c * b2ps[tid])));
        a2v[tid] = a2x;
        const float v6 = dpp_allred64(a2x * a2x);
        if ((tid & 63) == 0) dpart[80 + (tid >> 6)] = v6;
      } else if (t > 0) {
        W2_UPD()
      }
      __syncthreads();

      // ======== Phase C1: z3 partials = a2 @ W3 -> csc ===================
      {
        float c0a = 0.f, c1a = 0.f;
#define C1_ROW(i)                                                             \
        { const float a2x = a2v[p * 16 + i];                                  \
          c0a += a2x * W3x_##i; c1a += a2x * W3y_##i; }
        ROWS16(C1_ROW)
        csc[(q * 2 + 0) * 17 + p] = c0a;
        csc[(q * 2 + 1) * 17 + p] = c1a;
      }
      __syncthreads();

      // ======== Phase CE: softmax (wave7, flagD) || W2 upd; then o2 ======
      {
        if (w == 7) {
          __builtin_amdgcn_s_setprio(1);
          const float s3c = sca[4], rb3c = sca[5];
          float s = 0.f;
#pragma unroll
          for (int pp = 0; pp < 16; pp++) s += csc[lane * 17 + pp];
          const float z3p = s3c * s;
          const float a3 = 1.f / (1.f + expf(-(z3p + rb3c * b3ps[lane])));
          const float e = expf(-a3);
          const float tot = dpp_allred64(e);
          const float outv = e / tot;
          const float d3 = (Tb[l * 64 + lane] - outv) * a3 * (1.f - a3);
          d3v[lane] = d3;
          const float b3n = rb3c * b3ps[lane] - LRC * d3;
          b3ps[lane] = b3n;
          const float v5 = dpp_allred64(z3p * d3);
          const float v7 = dpp_allred64(d3 * d3);
          const float v10 = dpp_allred64(b3n * b3n);
          if (lane == 0) { dpart[84] = v5; dpart[85] = v7; dpart[86] = v10; }
          __builtin_amdgcn_s_setprio(0);
          wave_fence();
          if (lane == 0) *(volatile int*)&flgi[2] = t;
        } else if (w < 4) {
          if (t > 0) { W2_UPD() }
          lds_spin((volatile int*)&flgi[2], t);
        } else {
          lds_spin((volatile int*)&flgi[2], t);
        }
        asm volatile("" ::: "memory");
        // E-part (all waves): o2 partials | fence | intra-wave reduce
        const float s3c = sca[4], rb2c = sca[3];
        const float d0 = d3v[q * 2 + 0], d1 = d3v[q * 2 + 1];
#define E1_ROW(i) scr[(p * 16 + i) * 33 + q] = W3x_##i * d0 + W3y_##i * d1;
        ROWS16(E1_ROW)
        wave_fence();
        float s = 0.f;
#pragma unroll
        for (int qq = 0; qq < 32; qq++) s += scr[rown * 33 + qq];
        const float a2x = a2v[rown];
        const float o2x = s3c * s * a2x * (1.f - a2x);
        const float b2n = rb2c * b2ps[rown] - LRC * o2x;
        const bool own = (lane & 32) == 0;
        if (own) { o2v[cur + rown] = o2x; b2ps[rown] = b2n; }
        const float v2 = dpp_allred64(own ? z2v[rown] * o2x : 0.f);
        const float v4 = dpp_allred64(own ? o2x * o2x : 0.f);
        const float v9 = dpp_allred64(own ? b2n * b2n : 0.f);
        if (lane == 0) {
          dpart[24 + w] = v2; dpart[32 + w] = v4; dpart[40 + w] = v9;
        }
      }
      __syncthreads();

      // ======== Phase F: o1 partials | fence | intra-wave reduce =========
      {
        const float s2c = sca[2], rb1c = sca[1];
        const f32x8 ov8 = *(const f32x8*)&o2v[cur + q * 8];
#define F_ROW(i)                                                              \
        { f32x8 tq = W2_##i * ov8; scr[(p * 16 + i) * 33 + q] = hsum8(tq); }
        ROWS16(F_ROW)
        wave_fence();
        float s = 0.f;
#pragma unroll
        for (int qq = 0; qq < 32; qq++) s += scr[rown * 33 + qq];
        const float a1x = a1v[cur + rown];
        const float o1x = s2c * s * a1x * (1.f - a1x);
        const float b1n = rb1c * b1ps[rown] - LRC * o1x;
        const float z1x = z1v[rown];
        const bool own = (lane & 32) == 0;
        if (own) { zo[l * 272 + rown] = o1x; b1ps[rown] = b1n; }
        const float v0 = dpp_allred64(own ? z1x * o1x : 0.f);
        const float v1 = dpp_allred64(own ? o1x * o1x : 0.f);
        const float v8 = dpp_allred64(own ? b1n * b1n : 0.f);
        if (lane == 0) {
          dpart[0 + w] = v0; dpart[8 + w] = v1; dpart[16 + w] = v8;
        }
      }
      __syncthreads();
    }

    // ---- tail: chains for step bs+63 (produce next-block sca; sca[8]
    //      carries c1 for step bs+64, copied to ch[0] after the flush)
    if (w == 0) chain0(63);
    else if (w == 7) chain7((bs + 63) & 1);
    __syncthreads();

    // ---- per-block flush of o1 (from zo) and c (from ch) to global
    {
#pragma unroll
      for (int u = 0; u < 4; u++) {
        const int chunk = tid + u * 512;          // 0..2047
        const int row = chunk >> 5, c8 = chunk & 31;
        *(f32x8*)(o1g + (bs + row) * 256 + c8 * 8) =
            *(const f32x8*)(zo + row * 272 + c8 * 8);
      }
      if (tid < 64) cg[bs + tid] = ch[tid];
      if (tid == 0) ch[0] = sca[8];   // seed next block's c1(bs+64)
    }
    // next block's prefix __syncthreads() drains these stores before reads
  }

  // ---- epilogue: apply deferred update of step 1023, write scaled outputs
  {
    const float cw2f = sca[6], cw3f = sca[7];
    const float s2f = sca[2], s3f = sca[4];
    // t=1023 parity: cur = 256 for both a1v and o2v
    const f32x8 o8s = cw2f * (*(const f32x8*)&o2v[256 + q * 8]);
    const float d0s = cw3f * d3v[q * 2], d1s = cw3f * d3v[q * 2 + 1];
#define FIN_ROW(i)                                                            \
    { const float a1o = a1v[256 + p * 16 + i];                                \
      W2_##i += a1o * o8s;                                                    \
      const float a2o = a2v[p * 16 + i];                                      \
      W3x_##i += a2o * d0s; W3y_##i += a2o * d1s;                             \
      const int row = p * 16 + i;                                             \
      *(f32x8*)(outW2 + row * 256 + q * 8) = s2f * W2_##i;                    \
      outW3[row * 64 + q * 2]     = s3f * W3x_##i;                            \
      outW3[row * 64 + q * 2 + 1] = s3f * W3y_##i; }
    ROWS16(FIN_ROW)
    if (tid == 0) sclg[0] = sca[0];
  }
}

// ---------------------------------------------------------------- launch ----
extern "C" void kernel_launch(void* const* d_in, const int* in_sizes, int n_in,
                              void* d_out, int out_size, void* d_ws,
                              size_t ws_size, hipStream_t stream) {
  (void)in_sizes; (void)n_in; (void)out_size; (void)ws_size;
  const float* X   = (const float*)d_in[0];
  const float* Tg  = (const float*)d_in[1];
  const float* W1g = (const float*)d_in[2];
  const float* b1g = (const float*)d_in[3];
  const float* W2g = (const float*)d_in[4];
  const float* b2g = (const float*)d_in[5];
  const float* W3g = (const float*)d_in[6];
  const float* b3g = (const float*)d_in[7];
  float* out = (float*)d_out;
  float* ws  = (float*)d_ws;

  float* G    = ws;
  float* Z10  = G + 1048576;
  float* o1g  = Z10 + 262144;
  float* cg   = o1g + 262144;
  float* sclg = cg + 1024;

  (void)hipFuncSetAttribute((const void*)k2_seq,
                            hipFuncAttributeMaxDynamicSharedMemorySize,
                            SMEM_BYTES);

  k_gram<<<dim3(16, 16), 256, 0, stream>>>(X, G);
  k_z10<<<dim3(4, 16), 256, 0, stream>>>(X, W1g, Z10);
  k2_seq<<<dim3(1), dim3(512), SMEM_BYTES, stream>>>(
      Tg, W1g, b1g, W2g, b2g, W3g, b3g, G, Z10, o1g, cg, sclg,
      out + 262144, out + 327680);
  k_w1out<<<dim3(4, 16), 256, 0, stream>>>(X, o1g, cg, W1g, sclg, out);
}